// Round 4
// baseline (2443.316 us; speedup 1.0000x reference)
//
#include <hip/hip_runtime.h>

#define Bsz 128
#define Tn  1024
#define Dn  256
#define Hn  256

typedef _Float16 f16;
typedef _Float16 f16x4 __attribute__((ext_vector_type(4)));
typedef _Float16 f16x8 __attribute__((ext_vector_type(8)));
typedef float f32x4 __attribute__((ext_vector_type(4)));

#define MF(A, B, C) __builtin_amdgcn_mfma_f32_16x16x32_f16((A), (B), (C), 0, 0, 0)

// Cross-WG h1 stream: [g][t][4096 f16 frag-major] as u64. 64 MiB static
// device BSS (zero-init at load; no workspace growth). Forward-only flags:
// g_flag[g*64] = number of h1 steps published by producer g. Consumer resets
// its flag to 0 at kernel end -> clean state for graph replays.
__device__ unsigned long long g_h1[8ull * 1024 * 1024];
__device__ int g_flag[8 * 64];

// Exact tanh: 1 - 2/(e^{2x}+1) via v_exp_f32. err ~1e-6, saturates correctly.
__device__ __forceinline__ float tanh_fast(float x) {
    float e = __builtin_amdgcn_exp2f(x * 2.88539008177793f);  // e^{2x}
    return 1.0f - 2.0f * __builtin_amdgcn_rcpf(e + 1.0f);
}

// LDS-only barrier (lgkmcnt drain, no vmcnt) so global prefetch loads stay
// in flight across steps. All global loads are consumed by the issuing lane.
__device__ __forceinline__ void wg_barrier() {
    asm volatile("s_waitcnt lgkmcnt(0)\n\ts_barrier" ::: "memory");
}

// h fragment-major layout: element (m=batch 0..15, k=0..255) lives at
// f16 offset (k>>5)*512 + ((k>>3)&3)*128 + m*8 + (k&7).
// A wave's B-fragment read for K-block kk is then 16B at kk*512 + lane*8
// -> stride-1 lane-contiguous, conflict-free (LDS) / coalesced (global).

// ---------------------------------------------------------------------------
// K1: pre[t][b][j] = x[b][t][:] . Wxh0[j][:] + b0[j]   (fp32 in/out)
// grid = Tn WGs (one t each), 256 thr (4 waves x 64 j-cols).  [UNCHANGED]
// ---------------------------------------------------------------------------
__global__ __launch_bounds__(256, 2) void k_xproj(
    const float* __restrict__ x, const float* __restrict__ W,
    const float* __restrict__ bias, float* __restrict__ preT)
{
    __shared__ __align__(16) f16 xt[128][264];
    const int tid = threadIdx.x;
    const int t = blockIdx.x;

    for (int i = tid; i < 128 * 64; i += 256) {
        int row = i >> 6, c4 = i & 63;
        float4 v = *(const float4*)(x + ((size_t)row * Tn + t) * Dn + c4 * 4);
        f16x4 tv = { (f16)v.x, (f16)v.y, (f16)v.z, (f16)v.w };
        *(f16x4*)(&xt[row][c4 * 4]) = tv;
    }

    const int lane = tid & 63, l15 = lane & 15, quad = lane >> 4;
    const int w = tid >> 6;

    f16x8 wf[4][8];
    #pragma unroll
    for (int jn = 0; jn < 4; jn++) {
        int j = w * 64 + jn * 16 + l15;
        #pragma unroll
        for (int kk = 0; kk < 8; kk++)
            #pragma unroll
            for (int e = 0; e < 8; e++)
                wf[jn][kk][e] = (f16)W[(size_t)j * Dn + kk * 32 + quad * 8 + e];
    }
    float4 bi[4];
    #pragma unroll
    for (int jn = 0; jn < 4; jn++)
        bi[jn] = *(const float4*)(bias + w * 64 + jn * 16 + quad * 4);

    __syncthreads();

    #pragma unroll 1
    for (int bblk = 0; bblk < 8; bblk++) {
        f32x4 acc[4];
        #pragma unroll
        for (int jn = 0; jn < 4; jn++)
            acc[jn] = (f32x4){bi[jn].x, bi[jn].y, bi[jn].z, bi[jn].w};
        #pragma unroll
        for (int kk = 0; kk < 8; kk++) {
            f16x8 xb = *(const f16x8*)(&xt[bblk * 16 + l15][kk * 32 + quad * 8]);
            #pragma unroll
            for (int jn = 0; jn < 4; jn++)
                acc[jn] = MF(wf[jn][kk], xb, acc[jn]);
        }
        #pragma unroll
        for (int jn = 0; jn < 4; jn++) {
            int j0 = w * 64 + jn * 16 + quad * 4;
            *(f32x4*)(preT + ((size_t)t * Bsz + bblk * 16 + l15) * Hn + j0) = acc[jn];
        }
    }
}

// ---------------------------------------------------------------------------
// K2 (producer-consumer layer pipeline, 16 WGs x 512 thr):
//   blocks 0..7  (producer, group g): h1[t] = tanh(pre[t] + Whh0.h1[t-1]);
//     publishes h1[t] frag-major to g_h1[g][t] via agent-scope u64 stores;
//     per step: vmcnt(0) drain -> s_barrier -> tid0 flag = t+1 (release).
//     Forward-only flags + full-depth buffer => producer NEVER waits.
//   blocks 8..15 (consumer, group g): h2[t] = tanh(b1 + Wxh1.h1[t] +
//     Whh1.h2[t-1]); h1[t] fragments live in registers (double-buffered,
//     prefetched one step ahead under the MFMAs; flag also prefetched so the
//     agent-load latency is off the critical path after ~2-step startup lag).
//     Consumer is the bound: 2 waves/SIMD x 32 MFMA x 16cy = 1024 cy/step.
// ---------------------------------------------------------------------------
__global__ __launch_bounds__(512, 1) void k_fused(
    const float* __restrict__ Whh0, const float* __restrict__ Wxh1,
    const float* __restrict__ Whh1, const float* __restrict__ b1v,
    const float* __restrict__ fcw,  const float* __restrict__ fcb,
    const float* __restrict__ preT, float* __restrict__ out)
{
    __shared__ __align__(16) f16 hbuf[2][4096];  // producer: h1; consumer: h2

    const int tid  = threadIdx.x;
    const int lane = tid & 63, l15 = lane & 15, quad = lane >> 4;
    const int w    = tid >> 6;
    const int colbase = w * 32;
    const int gidx = blockIdx.x & 7;
    const int bg   = gidx * 16;

    for (int i = tid; i < 8192; i += 512) ((f16*)hbuf)[i] = (f16)0.0f;

    // write offsets (per jn): 4 consecutive k = n0..n0+3, frag-major
    int wroff[2];
    #pragma unroll
    for (int jn = 0; jn < 2; jn++) {
        int n0 = colbase + jn * 16 + quad * 4;
        wroff[jn] = (n0 >> 5) * 512 + ((n0 >> 3) & 3) * 128 + l15 * 8 + (n0 & 7);
    }

    unsigned long long* hg = g_h1 + (size_t)gidx * (1024 * 1024);
    int* flagp = &g_flag[gidx * 64];

    if (blockIdx.x < 8) {
        // ================= PRODUCER (layer 1) =================
        f16x8 wh0[2][8];
        #pragma unroll
        for (int jn = 0; jn < 2; jn++) {
            int j = colbase + jn * 16 + l15;
            #pragma unroll
            for (int kk = 0; kk < 8; kk++)
                #pragma unroll
                for (int e = 0; e < 8; e++)
                    wh0[jn][kk][e] = (f16)Whh0[(size_t)j * Hn + kk * 32 + quad * 8 + e];
        }
        const float* pp = preT + ((size_t)(bg + l15)) * Hn + colbase + quad * 4;
        f32x4 pnv0 = *(const f32x4*)(pp);
        f32x4 pnv1 = *(const f32x4*)(pp + 16);
        __syncthreads();

// Step I (parity P=I&1): read h1[I-1] from hbuf[P^1], write h1[I] to hbuf[P]
// + publish to g_h1. TF = prefetch step for pre.
#define PSTEP(P, I, TF) { \
    f32x4 accA[2]; \
    accA[0] = pnv0; accA[1] = pnv1; \
    pnv0 = *(const f32x4*)(pp + (size_t)(TF) * (Bsz * Hn)); \
    pnv1 = *(const f32x4*)(pp + (size_t)(TF) * (Bsz * Hn) + 16); \
    _Pragma("unroll") for (int kk = 0; kk < 8; kk++) { \
        f16x8 hb = *(const f16x8*)(&hbuf[(P)^1][kk * 512 + lane * 8]); \
        accA[0] = MF(wh0[0][kk], hb, accA[0]); \
        accA[1] = MF(wh0[1][kk], hb, accA[1]); \
    } \
    _Pragma("unroll") for (int jn = 0; jn < 2; jn++) { \
        union { f16x4 v; unsigned long long u; } t1; \
        t1.v = (f16x4){ (f16)tanh_fast(accA[jn][0]), (f16)tanh_fast(accA[jn][1]), \
                        (f16)tanh_fast(accA[jn][2]), (f16)tanh_fast(accA[jn][3]) }; \
        *(f16x4*)(&hbuf[(P)][wroff[jn]]) = t1.v; \
        __hip_atomic_store(hg + (size_t)(I) * 1024 + (wroff[jn] >> 2), t1.u, \
                           __ATOMIC_RELAXED, __HIP_MEMORY_SCOPE_AGENT); \
    } \
    asm volatile("s_waitcnt vmcnt(0) lgkmcnt(0)\n\ts_barrier" ::: "memory"); \
    if (tid == 0) \
        __hip_atomic_store(flagp, (I) + 1, __ATOMIC_RELEASE, __HIP_MEMORY_SCOPE_AGENT); \
}

        #pragma unroll 1
        for (int tp = 0; tp < 511; ++tp) {
            const int t0 = 2 * tp;
            PSTEP(0, t0, (t0 + 1))
            PSTEP(1, (t0 + 1), (t0 + 2))
        }
        PSTEP(0, 1022, 1023)
        PSTEP(1, 1023, 1023)   // prefetch clamped (unused afterwards)
#undef PSTEP
    } else {
        // ================= CONSUMER (layer 2 + head) =================
        f16x8 wx[2][8], wh1[2][8];
        #pragma unroll
        for (int jn = 0; jn < 2; jn++) {
            int j = colbase + jn * 16 + l15;
            #pragma unroll
            for (int kk = 0; kk < 8; kk++)
                #pragma unroll
                for (int e = 0; e < 8; e++) {
                    int o = (int)((size_t)j * Hn + kk * 32 + quad * 8 + e);
                    wx [jn][kk][e] = (f16)Wxh1[o];
                    wh1[jn][kk][e] = (f16)Whh1[o];
                }
        }
        float4 bi[2];
        #pragma unroll
        for (int jn = 0; jn < 2; jn++)
            bi[jn] = *(const float4*)(b1v + colbase + jn * 16 + quad * 4);
        __syncthreads();

        // startup: wait for h1[0], load it into bufA
        int fval = __hip_atomic_load(flagp, __ATOMIC_RELAXED, __HIP_MEMORY_SCOPE_AGENT);
        while (fval < 1) {
            __builtin_amdgcn_s_sleep(2);
            fval = __hip_atomic_load(flagp, __ATOMIC_RELAXED, __HIP_MEMORY_SCOPE_AGENT);
        }
        __builtin_amdgcn_fence(__ATOMIC_ACQUIRE, "agent");
        f16x8 bufA[8], bufB[8];
        {
            unsigned long long* hp = hg + lane * 2;
            #pragma unroll
            for (int kk = 0; kk < 8; kk++) {
                union { unsigned long long u[2]; f16x8 v; } tb;
                tb.u[0] = __hip_atomic_load(hp + kk * 128,     __ATOMIC_RELAXED, __HIP_MEMORY_SCOPE_AGENT);
                tb.u[1] = __hip_atomic_load(hp + kk * 128 + 1, __ATOMIC_RELAXED, __HIP_MEMORY_SCOPE_AGENT);
                bufA[kk] = tb.v;
            }
        }
        fval = __hip_atomic_load(flagp, __ATOMIC_RELAXED, __HIP_MEMORY_SCOPE_AGENT);

// Step I (parity P=I&1): h2[I] = tanh(b1 + Wxh1.h1[I](CURB) + Whh1.h2[I-1]
// (hbuf[P])), write hbuf[P^1]. Prefetch h1[I+1] -> NXTB (needs flag >= I+2;
// fval is the one-step-stale prefetched flag; spin only if behind).
#define CSTEP(P, I, CURB, NXTB) { \
    int fchk = fval; \
    fval = __hip_atomic_load(flagp, __ATOMIC_RELAXED, __HIP_MEMORY_SCOPE_AGENT); \
    if (fchk < (I) + 2) { \
        do { __builtin_amdgcn_s_sleep(2); \
             fchk = __hip_atomic_load(flagp, __ATOMIC_RELAXED, __HIP_MEMORY_SCOPE_AGENT); \
        } while (fchk < (I) + 2); \
        fval = fchk; \
    } \
    __builtin_amdgcn_fence(__ATOMIC_ACQUIRE, "agent"); \
    { unsigned long long* hp = hg + (size_t)((I) + 1) * 1024 + lane * 2; \
      _Pragma("unroll") for (int kk = 0; kk < 8; kk++) { \
        union { unsigned long long u[2]; f16x8 v; } tb; \
        tb.u[0] = __hip_atomic_load(hp + kk * 128,     __ATOMIC_RELAXED, __HIP_MEMORY_SCOPE_AGENT); \
        tb.u[1] = __hip_atomic_load(hp + kk * 128 + 1, __ATOMIC_RELAXED, __HIP_MEMORY_SCOPE_AGENT); \
        NXTB[kk] = tb.v; } } \
    f32x4 accB[2]; \
    accB[0] = (f32x4){bi[0].x, bi[0].y, bi[0].z, bi[0].w}; \
    accB[1] = (f32x4){bi[1].x, bi[1].y, bi[1].z, bi[1].w}; \
    _Pragma("unroll") for (int kk = 0; kk < 8; kk++) { \
        f16x8 hb2 = *(const f16x8*)(&hbuf[(P)][kk * 512 + lane * 8]); \
        accB[0] = MF(wx [0][kk], CURB[kk], accB[0]); \
        accB[1] = MF(wx [1][kk], CURB[kk], accB[1]); \
        accB[0] = MF(wh1[0][kk], hb2, accB[0]); \
        accB[1] = MF(wh1[1][kk], hb2, accB[1]); \
    } \
    _Pragma("unroll") for (int jn = 0; jn < 2; jn++) { \
        f16x4 t2v = { (f16)tanh_fast(accB[jn][0]), (f16)tanh_fast(accB[jn][1]), \
                      (f16)tanh_fast(accB[jn][2]), (f16)tanh_fast(accB[jn][3]) }; \
        *(f16x4*)(&hbuf[(P)^1][wroff[jn]]) = t2v; \
    } \
    wg_barrier(); \
}
// Last step: no flag wait / no prefetch.
#define CSTEP_LAST(P, CURB) { \
    f32x4 accB[2]; \
    accB[0] = (f32x4){bi[0].x, bi[0].y, bi[0].z, bi[0].w}; \
    accB[1] = (f32x4){bi[1].x, bi[1].y, bi[1].z, bi[1].w}; \
    _Pragma("unroll") for (int kk = 0; kk < 8; kk++) { \
        f16x8 hb2 = *(const f16x8*)(&hbuf[(P)][kk * 512 + lane * 8]); \
        accB[0] = MF(wx [0][kk], CURB[kk], accB[0]); \
        accB[1] = MF(wx [1][kk], CURB[kk], accB[1]); \
        accB[0] = MF(wh1[0][kk], hb2, accB[0]); \
        accB[1] = MF(wh1[1][kk], hb2, accB[1]); \
    } \
    _Pragma("unroll") for (int jn = 0; jn < 2; jn++) { \
        f16x4 t2v = { (f16)tanh_fast(accB[jn][0]), (f16)tanh_fast(accB[jn][1]), \
                      (f16)tanh_fast(accB[jn][2]), (f16)tanh_fast(accB[jn][3]) }; \
        *(f16x4*)(&hbuf[(P)^1][wroff[jn]]) = t2v; \
    } \
    wg_barrier(); \
}

        #pragma unroll 1
        for (int tp = 0; tp < 511; ++tp) {
            const int t0 = 2 * tp;
            CSTEP(0, t0, bufA, bufB)
            CSTEP(1, (t0 + 1), bufB, bufA)
        }
        CSTEP(0, 1022, bufA, bufB)   // prefetches h1[1023], needs flag >= 1024
        CSTEP_LAST(1, bufB)          // i = 1023 -> writes hbuf[0]
#undef CSTEP
#undef CSTEP_LAST

        // head: final h2[1023] in hbuf[0]; frag-major.
        if (tid < 256) {
            const int bl = tid >> 4, o = (tid >> 3) & 1, kc = tid & 7;
            float s = 0.f;
            #pragma unroll
            for (int kq = 0; kq < 32; kq++) {
                int k = kc * 32 + kq;
                f16 hv = hbuf[0][(k >> 5) * 512 + ((k >> 3) & 3) * 128 + bl * 8 + (k & 7)];
                s += (float)hv * fcw[o * Hn + k];
            }
            s += __shfl_down(s, 4);
            s += __shfl_down(s, 2);
            s += __shfl_down(s, 1);
            if (kc == 0)
                out[(bg + bl) * 2 + o] = s + fcb[o];
        }

        // self-clean flags for the next launch / graph replay
        if (tid == 0)
            __hip_atomic_store(flagp, 0, __ATOMIC_RELEASE, __HIP_MEMORY_SCOPE_AGENT);
    }
}

extern "C" void kernel_launch(void* const* d_in, const int* in_sizes, int n_in,
                              void* d_out, int out_size, void* d_ws, size_t ws_size,
                              hipStream_t stream) {
    const float* x    = (const float*)d_in[0];
    const float* Wxh0 = (const float*)d_in[1];
    const float* Whh0 = (const float*)d_in[2];
    const float* b0   = (const float*)d_in[3];
    const float* Wxh1 = (const float*)d_in[4];
    const float* Whh1 = (const float*)d_in[5];
    const float* b1   = (const float*)d_in[6];
    const float* fcw  = (const float*)d_in[7];
    const float* fcb  = (const float*)d_in[8];
    float* out = (float*)d_out;

    float* preT = (float*)d_ws;  // pre[t][b][j] fp32 = 128 MiB

    k_xproj<<<dim3(Tn), dim3(256), 0, stream>>>(x, Wxh0, b0, preT);
    k_fused<<<dim3(16), dim3(512), 0, stream>>>(Whh0, Wxh1, Whh1, b1,
                                                fcw, fcb, preT, out);
}

// Round 5
// 2360.953 us; speedup vs baseline: 1.0349x; 1.0349x over previous
//
#include <hip/hip_runtime.h>

#define Bsz 128
#define Tn  1024
#define Dn  256
#define Hn  256

typedef _Float16 f16;
typedef _Float16 f16x4 __attribute__((ext_vector_type(4)));
typedef _Float16 f16x8 __attribute__((ext_vector_type(8)));
typedef float f32x4 __attribute__((ext_vector_type(4)));

#define MF(A, B, C) __builtin_amdgcn_mfma_f32_16x16x32_f16((A), (B), (C), 0, 0, 0)

// Cross-WG h1 stream: [g][t][4096 f16 frag-major] as u64. 64 MiB static
// device BSS. Forward-only flags: g_flag[g*64] = count of h1 steps globally
// visible. Consumer resets its flag at kernel end (clean for graph replays).
__device__ unsigned long long g_h1[8ull * 1024 * 1024];
__device__ int g_flag[8 * 64];

// Exact tanh: 1 - 2/(e^{2x}+1) via v_exp_f32. err ~1e-6, saturates correctly.
__device__ __forceinline__ float tanh_fast(float x) {
    float e = __builtin_amdgcn_exp2f(x * 2.88539008177793f);  // e^{2x}
    return 1.0f - 2.0f * __builtin_amdgcn_rcpf(e + 1.0f);
}

// LDS-only barrier (lgkmcnt drain, no vmcnt) so global loads/stores stay
// in flight across steps.
__device__ __forceinline__ void wg_barrier() {
    asm volatile("s_waitcnt lgkmcnt(0)\n\ts_barrier" ::: "memory");
}

// h fragment-major layout: element (m=batch 0..15, k=0..255) lives at
// f16 offset (k>>5)*512 + ((k>>3)&3)*128 + m*8 + (k&7).
// A wave's B-fragment read for K-block kk is then 16B at kk*512 + lane*8
// -> stride-1 lane-contiguous, conflict-free (LDS) / coalesced (global).

// ---------------------------------------------------------------------------
// K1: pre[t][b][j] = x[b][t][:] . Wxh0[j][:] + b0[j]   (fp32 in/out)
// grid = 256 WGs x 4 timesteps each (amortizes the weight-fragment load,
// which dominated the 1-t-per-WG version), 256 thr (4 waves x 64 j-cols).
// Weight fragments loaded VECTORIZED (2x float4 per kk, not 8 scalars).
// ---------------------------------------------------------------------------
__global__ __launch_bounds__(256, 2) void k_xproj(
    const float* __restrict__ x, const float* __restrict__ W,
    const float* __restrict__ bias, float* __restrict__ preT)
{
    __shared__ __align__(16) f16 xt[128][264];
    const int tid = threadIdx.x;
    const int tbase = blockIdx.x * 4;

    const int lane = tid & 63, l15 = lane & 15, quad = lane >> 4;
    const int w = tid >> 6;

    // A-fragments of Wxh0 (j = w*64 + jn*16 + l15, k = kk*32 + quad*8 + e)
    f16x8 wf[4][8];
    #pragma unroll
    for (int jn = 0; jn < 4; jn++) {
        int j = w * 64 + jn * 16 + l15;
        #pragma unroll
        for (int kk = 0; kk < 8; kk++) {
            const float* wp = W + (size_t)j * Dn + kk * 32 + quad * 8;
            float4 a = *(const float4*)(wp);
            float4 b = *(const float4*)(wp + 4);
            wf[jn][kk] = (f16x8){ (f16)a.x, (f16)a.y, (f16)a.z, (f16)a.w,
                                  (f16)b.x, (f16)b.y, (f16)b.z, (f16)b.w };
        }
    }
    float4 bi[4];
    #pragma unroll
    for (int jn = 0; jn < 4; jn++)
        bi[jn] = *(const float4*)(bias + w * 64 + jn * 16 + quad * 4);

    #pragma unroll 1
    for (int tt = 0; tt < 4; tt++) {
        const int t = tbase + tt;
        __syncthreads();   // previous iteration's xt reads complete
        for (int i = tid; i < 128 * 64; i += 256) {
            int row = i >> 6, c4 = i & 63;
            float4 v = *(const float4*)(x + ((size_t)row * Tn + t) * Dn + c4 * 4);
            f16x4 tv = { (f16)v.x, (f16)v.y, (f16)v.z, (f16)v.w };
            *(f16x4*)(&xt[row][c4 * 4]) = tv;
        }
        __syncthreads();

        #pragma unroll 1
        for (int bblk = 0; bblk < 8; bblk++) {
            f32x4 acc[4];
            #pragma unroll
            for (int jn = 0; jn < 4; jn++)
                acc[jn] = (f32x4){bi[jn].x, bi[jn].y, bi[jn].z, bi[jn].w};
            #pragma unroll
            for (int kk = 0; kk < 8; kk++) {
                f16x8 xb = *(const f16x8*)(&xt[bblk * 16 + l15][kk * 32 + quad * 8]);
                #pragma unroll
                for (int jn = 0; jn < 4; jn++)
                    acc[jn] = MF(wf[jn][kk], xb, acc[jn]);
            }
            #pragma unroll
            for (int jn = 0; jn < 4; jn++) {
                int j0 = w * 64 + jn * 16 + quad * 4;
                *(f32x4*)(preT + ((size_t)t * Bsz + bblk * 16 + l15) * Hn + j0) = acc[jn];
            }
        }
    }
}

// ---------------------------------------------------------------------------
// K2 (producer-consumer layer pipeline, 16 WGs x 512 thr):
//   blocks 0..7  (producer, group g): h1[t] = tanh(pre[t] + Whh0.h1[t-1]);
//     publishes h1[t] to g_h1[g][t] via relaxed agent u64 stores. COUNTED
//     drain: each step issues exactly 4 VMEM ops/lane (2 pre-loads, 2 h1
//     stores); end-of-step `s_waitcnt vmcnt(8)` => all stores through step
//     I-2 retired (r4's per-step vmcnt(0) was the 2x regression: a full
//     coherence-point round trip on the critical path). After the barrier,
//     tid0 publishes flag = I-1 RELAXED (release would re-emit vmcnt(0);
//     ordering is already guaranteed by the counted wait + barrier).
//     Epilogue: vmcnt(0) once, flag = 1024. Producer NEVER waits.
//   blocks 8..15 (consumer, group g): h2[t] = tanh(b1 + Wxh1.h1[t] +
//     Whh1.h2[t-1]); h1 fragments double-buffered in registers, prefetched
//     one step ahead under the MFMAs. Producer step (~1000cy) < consumer
//     step (~1350cy) => after ~3-step warmup the flag check never spins.
// ---------------------------------------------------------------------------
__global__ __launch_bounds__(512, 1) void k_fused(
    const float* __restrict__ Whh0, const float* __restrict__ Wxh1,
    const float* __restrict__ Whh1, const float* __restrict__ b1v,
    const float* __restrict__ fcw,  const float* __restrict__ fcb,
    const float* __restrict__ preT, float* __restrict__ out)
{
    __shared__ __align__(16) f16 hbuf[2][4096];  // producer: h1; consumer: h2

    const int tid  = threadIdx.x;
    const int lane = tid & 63, l15 = lane & 15, quad = lane >> 4;
    const int w    = tid >> 6;
    const int colbase = w * 32;
    const int gidx = blockIdx.x & 7;
    const int bg   = gidx * 16;

    for (int i = tid; i < 8192; i += 512) ((f16*)hbuf)[i] = (f16)0.0f;

    int wroff[2];
    #pragma unroll
    for (int jn = 0; jn < 2; jn++) {
        int n0 = colbase + jn * 16 + quad * 4;
        wroff[jn] = (n0 >> 5) * 512 + ((n0 >> 3) & 3) * 128 + l15 * 8 + (n0 & 7);
    }

    unsigned long long* hg = g_h1 + (size_t)gidx * (1024 * 1024);
    int* flagp = &g_flag[gidx * 64];

    if (blockIdx.x < 8) {
        // ================= PRODUCER (layer 1) =================
        f16x8 wh0[2][8];
        #pragma unroll
        for (int jn = 0; jn < 2; jn++) {
            int j = colbase + jn * 16 + l15;
            #pragma unroll
            for (int kk = 0; kk < 8; kk++)
                #pragma unroll
                for (int e = 0; e < 8; e++)
                    wh0[jn][kk][e] = (f16)Whh0[(size_t)j * Hn + kk * 32 + quad * 8 + e];
        }
        const float* pp = preT + ((size_t)(bg + l15)) * Hn + colbase + quad * 4;
        f32x4 pnv0 = *(const f32x4*)(pp);
        f32x4 pnv1 = *(const f32x4*)(pp + 16);
        __syncthreads();

// Step I (parity P=I&1): read h1[I-1] from hbuf[P^1], write h1[I] to hbuf[P]
// + publish to g_h1. Exactly 4 VMEM/lane/step (2 loads, 2 stores), in order.
#define PSTEP(P, I, TF) { \
    f32x4 accA[2]; \
    accA[0] = pnv0; accA[1] = pnv1; \
    pnv0 = *(const f32x4*)(pp + (size_t)(TF) * (Bsz * Hn)); \
    pnv1 = *(const f32x4*)(pp + (size_t)(TF) * (Bsz * Hn) + 16); \
    _Pragma("unroll") for (int kk = 0; kk < 8; kk++) { \
        f16x8 hb = *(const f16x8*)(&hbuf[(P)^1][kk * 512 + lane * 8]); \
        accA[0] = MF(wh0[0][kk], hb, accA[0]); \
        accA[1] = MF(wh0[1][kk], hb, accA[1]); \
    } \
    _Pragma("unroll") for (int jn = 0; jn < 2; jn++) { \
        union { f16x4 v; unsigned long long u; } t1; \
        t1.v = (f16x4){ (f16)tanh_fast(accA[jn][0]), (f16)tanh_fast(accA[jn][1]), \
                        (f16)tanh_fast(accA[jn][2]), (f16)tanh_fast(accA[jn][3]) }; \
        *(f16x4*)(&hbuf[(P)][wroff[jn]]) = t1.v; \
        __hip_atomic_store(hg + (size_t)(I) * 1024 + (wroff[jn] >> 2), t1.u, \
                           __ATOMIC_RELAXED, __HIP_MEMORY_SCOPE_AGENT); \
    } \
    asm volatile("s_waitcnt vmcnt(8)" ::: "memory"); /* steps <= I-2 retired */ \
    wg_barrier(); /* all waves past their vmcnt(8) */ \
    if (tid == 0 && (I) > 0) \
        __hip_atomic_store(flagp, (I) - 1 + 1, __ATOMIC_RELAXED, __HIP_MEMORY_SCOPE_AGENT); \
}
// NOTE: flag semantics = "h1[0..flag-1] visible". After step I, steps 0..I-2
// are retired => flag = I-1 ... stored as (I)-1+1 = I because step indices
// are 0-based and count = (I-2)+1 = I-1 ... keep it simple: count = I-1.
// The expression above stores I; that would over-claim by one. Fix below:
#undef PSTEP
#define PSTEP(P, I, TF) { \
    f32x4 accA[2]; \
    accA[0] = pnv0; accA[1] = pnv1; \
    pnv0 = *(const f32x4*)(pp + (size_t)(TF) * (Bsz * Hn)); \
    pnv1 = *(const f32x4*)(pp + (size_t)(TF) * (Bsz * Hn) + 16); \
    _Pragma("unroll") for (int kk = 0; kk < 8; kk++) { \
        f16x8 hb = *(const f16x8*)(&hbuf[(P)^1][kk * 512 + lane * 8]); \
        accA[0] = MF(wh0[0][kk], hb, accA[0]); \
        accA[1] = MF(wh0[1][kk], hb, accA[1]); \
    } \
    _Pragma("unroll") for (int jn = 0; jn < 2; jn++) { \
        union { f16x4 v; unsigned long long u; } t1; \
        t1.v = (f16x4){ (f16)tanh_fast(accA[jn][0]), (f16)tanh_fast(accA[jn][1]), \
                        (f16)tanh_fast(accA[jn][2]), (f16)tanh_fast(accA[jn][3]) }; \
        *(f16x4*)(&hbuf[(P)][wroff[jn]]) = t1.v; \
        __hip_atomic_store(hg + (size_t)(I) * 1024 + (wroff[jn] >> 2), t1.u, \
                           __ATOMIC_RELAXED, __HIP_MEMORY_SCOPE_AGENT); \
    } \
    asm volatile("s_waitcnt vmcnt(8)" ::: "memory"); /* steps <= I-2 retired */ \
    wg_barrier(); /* all waves past their vmcnt(8) */ \
    if (tid == 0 && (I) > 0) \
        __hip_atomic_store(flagp, (I) - 1, __ATOMIC_RELAXED, __HIP_MEMORY_SCOPE_AGENT); \
}

        #pragma unroll 1
        for (int tp = 0; tp < 511; ++tp) {
            const int t0 = 2 * tp;
            PSTEP(0, t0, (t0 + 1))
            PSTEP(1, (t0 + 1), (t0 + 2))
        }
        PSTEP(0, 1022, 1023)
        PSTEP(1, 1023, 1023)   // prefetch clamped (unused afterwards)
#undef PSTEP
        // epilogue: drain everything once, publish all 1024 steps
        asm volatile("s_waitcnt vmcnt(0)" ::: "memory");
        __syncthreads();
        if (tid == 0)
            __hip_atomic_store(flagp, 1024, __ATOMIC_RELAXED, __HIP_MEMORY_SCOPE_AGENT);
    } else {
        // ================= CONSUMER (layer 2 + head) =================
        f16x8 wx[2][8], wh1[2][8];
        #pragma unroll
        for (int jn = 0; jn < 2; jn++) {
            int j = colbase + jn * 16 + l15;
            #pragma unroll
            for (int kk = 0; kk < 8; kk++)
                #pragma unroll
                for (int e = 0; e < 8; e++) {
                    int o = (int)((size_t)j * Hn + kk * 32 + quad * 8 + e);
                    wx [jn][kk][e] = (f16)Wxh1[o];
                    wh1[jn][kk][e] = (f16)Whh1[o];
                }
        }
        float4 bi[2];
        #pragma unroll
        for (int jn = 0; jn < 2; jn++)
            bi[jn] = *(const float4*)(b1v + colbase + jn * 16 + quad * 4);
        __syncthreads();

        // startup: wait for h1[0], load it into bufA
        int fval = __hip_atomic_load(flagp, __ATOMIC_RELAXED, __HIP_MEMORY_SCOPE_AGENT);
        while (fval < 1) {
            __builtin_amdgcn_s_sleep(2);
            fval = __hip_atomic_load(flagp, __ATOMIC_RELAXED, __HIP_MEMORY_SCOPE_AGENT);
        }
        __builtin_amdgcn_fence(__ATOMIC_ACQUIRE, "agent");
        f16x8 bufA[8], bufB[8];
        {
            unsigned long long* hp = hg + lane * 2;
            #pragma unroll
            for (int kk = 0; kk < 8; kk++) {
                union { unsigned long long u[2]; f16x8 v; } tb;
                tb.u[0] = __hip_atomic_load(hp + kk * 128,     __ATOMIC_RELAXED, __HIP_MEMORY_SCOPE_AGENT);
                tb.u[1] = __hip_atomic_load(hp + kk * 128 + 1, __ATOMIC_RELAXED, __HIP_MEMORY_SCOPE_AGENT);
                bufA[kk] = tb.v;
            }
        }
        fval = __hip_atomic_load(flagp, __ATOMIC_RELAXED, __HIP_MEMORY_SCOPE_AGENT);

// Step I (parity P=I&1): h2[I] = tanh(b1 + Wxh1.h1[I](CURB) + Whh1.h2[I-1]
// (hbuf[P])), write hbuf[P^1]. Prefetch h1[I+1] -> NXTB (needs flag >= I+2;
// fval is the one-step-stale prefetched flag; spin only if behind).
#define CSTEP(P, I, CURB, NXTB) { \
    int fchk = fval; \
    fval = __hip_atomic_load(flagp, __ATOMIC_RELAXED, __HIP_MEMORY_SCOPE_AGENT); \
    if (fchk < (I) + 2) { \
        do { __builtin_amdgcn_s_sleep(2); \
             fchk = __hip_atomic_load(flagp, __ATOMIC_RELAXED, __HIP_MEMORY_SCOPE_AGENT); \
        } while (fchk < (I) + 2); \
        fval = fchk; \
    } \
    __builtin_amdgcn_fence(__ATOMIC_ACQUIRE, "agent"); \
    { unsigned long long* hp = hg + (size_t)((I) + 1) * 1024 + lane * 2; \
      _Pragma("unroll") for (int kk = 0; kk < 8; kk++) { \
        union { unsigned long long u[2]; f16x8 v; } tb; \
        tb.u[0] = __hip_atomic_load(hp + kk * 128,     __ATOMIC_RELAXED, __HIP_MEMORY_SCOPE_AGENT); \
        tb.u[1] = __hip_atomic_load(hp + kk * 128 + 1, __ATOMIC_RELAXED, __HIP_MEMORY_SCOPE_AGENT); \
        NXTB[kk] = tb.v; } } \
    f32x4 accB[2]; \
    accB[0] = (f32x4){bi[0].x, bi[0].y, bi[0].z, bi[0].w}; \
    accB[1] = (f32x4){bi[1].x, bi[1].y, bi[1].z, bi[1].w}; \
    _Pragma("unroll") for (int kk = 0; kk < 8; kk++) { \
        f16x8 hb2 = *(const f16x8*)(&hbuf[(P)][kk * 512 + lane * 8]); \
        accB[0] = MF(wx [0][kk], CURB[kk], accB[0]); \
        accB[1] = MF(wx [1][kk], CURB[kk], accB[1]); \
        accB[0] = MF(wh1[0][kk], hb2, accB[0]); \
        accB[1] = MF(wh1[1][kk], hb2, accB[1]); \
    } \
    _Pragma("unroll") for (int jn = 0; jn < 2; jn++) { \
        f16x4 t2v = { (f16)tanh_fast(accB[jn][0]), (f16)tanh_fast(accB[jn][1]), \
                      (f16)tanh_fast(accB[jn][2]), (f16)tanh_fast(accB[jn][3]) }; \
        *(f16x4*)(&hbuf[(P)^1][wroff[jn]]) = t2v; \
    } \
    wg_barrier(); \
}
// Last step: no flag wait / no prefetch.
#define CSTEP_LAST(P, CURB) { \
    f32x4 accB[2]; \
    accB[0] = (f32x4){bi[0].x, bi[0].y, bi[0].z, bi[0].w}; \
    accB[1] = (f32x4){bi[1].x, bi[1].y, bi[1].z, bi[1].w}; \
    _Pragma("unroll") for (int kk = 0; kk < 8; kk++) { \
        f16x8 hb2 = *(const f16x8*)(&hbuf[(P)][kk * 512 + lane * 8]); \
        accB[0] = MF(wx [0][kk], CURB[kk], accB[0]); \
        accB[1] = MF(wx [1][kk], CURB[kk], accB[1]); \
        accB[0] = MF(wh1[0][kk], hb2, accB[0]); \
        accB[1] = MF(wh1[1][kk], hb2, accB[1]); \
    } \
    _Pragma("unroll") for (int jn = 0; jn < 2; jn++) { \
        f16x4 t2v = { (f16)tanh_fast(accB[jn][0]), (f16)tanh_fast(accB[jn][1]), \
                      (f16)tanh_fast(accB[jn][2]), (f16)tanh_fast(accB[jn][3]) }; \
        *(f16x4*)(&hbuf[(P)^1][wroff[jn]]) = t2v; \
    } \
    wg_barrier(); \
}

        #pragma unroll 1
        for (int tp = 0; tp < 511; ++tp) {
            const int t0 = 2 * tp;
            CSTEP(0, t0, bufA, bufB)
            CSTEP(1, (t0 + 1), bufB, bufA)
        }
        CSTEP(0, 1022, bufA, bufB)   // prefetches h1[1023], needs flag >= 1024
        CSTEP_LAST(1, bufB)          // i = 1023 -> writes hbuf[0]
#undef CSTEP
#undef CSTEP_LAST

        // head: final h2[1023] in hbuf[0]; frag-major.
        if (tid < 256) {
            const int bl = tid >> 4, o = (tid >> 3) & 1, kc = tid & 7;
            float s = 0.f;
            #pragma unroll
            for (int kq = 0; kq < 32; kq++) {
                int k = kc * 32 + kq;
                f16 hv = hbuf[0][(k >> 5) * 512 + ((k >> 3) & 3) * 128 + bl * 8 + (k & 7)];
                s += (float)hv * fcw[o * Hn + k];
            }
            s += __shfl_down(s, 4);
            s += __shfl_down(s, 2);
            s += __shfl_down(s, 1);
            if (kc == 0)
                out[(bg + bl) * 2 + o] = s + fcb[o];
        }

        // self-clean flags for the next launch / graph replay
        if (tid == 0)
            __hip_atomic_store(flagp, 0, __ATOMIC_RELEASE, __HIP_MEMORY_SCOPE_AGENT);
    }
}

extern "C" void kernel_launch(void* const* d_in, const int* in_sizes, int n_in,
                              void* d_out, int out_size, void* d_ws, size_t ws_size,
                              hipStream_t stream) {
    const float* x    = (const float*)d_in[0];
    const float* Wxh0 = (const float*)d_in[1];
    const float* Whh0 = (const float*)d_in[2];
    const float* b0   = (const float*)d_in[3];
    const float* Wxh1 = (const float*)d_in[4];
    const float* Whh1 = (const float*)d_in[5];
    const float* b1   = (const float*)d_in[6];
    const float* fcw  = (const float*)d_in[7];
    const float* fcb  = (const float*)d_in[8];
    float* out = (float*)d_out;

    float* preT = (float*)d_ws;  // pre[t][b][j] fp32 = 128 MiB

    k_xproj<<<dim3(256), dim3(256), 0, stream>>>(x, Wxh0, b0, preT);
    k_fused<<<dim3(16),  dim3(512), 0, stream>>>(Whh0, Wxh1, Whh1, b1,
                                                 fcw, fcb, preT, out);
}

// Round 6
// 1731.040 us; speedup vs baseline: 1.4115x; 1.3639x over previous
//
#include <hip/hip_runtime.h>

#define Bsz 128
#define Tn  1024
#define Dn  256
#define Hn  256

typedef _Float16 f16;
typedef _Float16 f16x4 __attribute__((ext_vector_type(4)));
typedef _Float16 f16x8 __attribute__((ext_vector_type(8)));
typedef float f32x4 __attribute__((ext_vector_type(4)));

#define MF(A, B, C) __builtin_amdgcn_mfma_f32_16x16x32_f16((A), (B), (C), 0, 0, 0)

// Cross-WG h1 stream: [g][t][4096 f16 frag-major] as u64. 64 MiB static BSS.
// g_flag[g*64] = number of h1 steps RETIRED to the coherence point.
// Consumer resets its flag at kernel end (clean state for graph replays).
__device__ unsigned long long g_h1[8ull * 1024 * 1024];
__device__ int g_flag[8 * 64];

// Exact tanh: 1 - 2/(e^{2x}+1) via v_exp_f32. err ~1e-6, saturates correctly.
__device__ __forceinline__ float tanh_fast(float x) {
    float e = __builtin_amdgcn_exp2f(x * 2.88539008177793f);  // e^{2x}
    return 1.0f - 2.0f * __builtin_amdgcn_rcpf(e + 1.0f);
}

// LDS-only barrier (lgkmcnt drain, no vmcnt): global loads/stores stay in
// flight across steps.
__device__ __forceinline__ void wg_barrier() {
    asm volatile("s_waitcnt lgkmcnt(0)\n\ts_barrier" ::: "memory");
}

// h fragment-major layout: element (m=batch 0..15, k=0..255) lives at
// f16 offset (k>>5)*512 + ((k>>3)&3)*128 + m*8 + (k&7).
// A wave's B-fragment read for K-block kk is 16B at kk*512 + lane*8
// -> stride-1 lane-contiguous, conflict-free (LDS) / coalesced (global).

// ---------------------------------------------------------------------------
// K1: pre[t][b][j] = x[b][t][:] . Wxh0[j][:] + b0[j]   (fp32 in/out)
// grid = 256 WGs x 4 timesteps each, 256 thr (4 waves x 64 j-cols).
// [UNCHANGED from r5]
// ---------------------------------------------------------------------------
__global__ __launch_bounds__(256, 2) void k_xproj(
    const float* __restrict__ x, const float* __restrict__ W,
    const float* __restrict__ bias, float* __restrict__ preT)
{
    __shared__ __align__(16) f16 xt[128][264];
    const int tid = threadIdx.x;
    const int tbase = blockIdx.x * 4;

    const int lane = tid & 63, l15 = lane & 15, quad = lane >> 4;
    const int w = tid >> 6;

    f16x8 wf[4][8];
    #pragma unroll
    for (int jn = 0; jn < 4; jn++) {
        int j = w * 64 + jn * 16 + l15;
        #pragma unroll
        for (int kk = 0; kk < 8; kk++) {
            const float* wp = W + (size_t)j * Dn + kk * 32 + quad * 8;
            float4 a = *(const float4*)(wp);
            float4 b = *(const float4*)(wp + 4);
            wf[jn][kk] = (f16x8){ (f16)a.x, (f16)a.y, (f16)a.z, (f16)a.w,
                                  (f16)b.x, (f16)b.y, (f16)b.z, (f16)b.w };
        }
    }
    float4 bi[4];
    #pragma unroll
    for (int jn = 0; jn < 4; jn++)
        bi[jn] = *(const float4*)(bias + w * 64 + jn * 16 + quad * 4);

    #pragma unroll 1
    for (int tt = 0; tt < 4; tt++) {
        const int t = tbase + tt;
        __syncthreads();
        for (int i = tid; i < 128 * 64; i += 256) {
            int row = i >> 6, c4 = i & 63;
            float4 v = *(const float4*)(x + ((size_t)row * Tn + t) * Dn + c4 * 4);
            f16x4 tv = { (f16)v.x, (f16)v.y, (f16)v.z, (f16)v.w };
            *(f16x4*)(&xt[row][c4 * 4]) = tv;
        }
        __syncthreads();

        #pragma unroll 1
        for (int bblk = 0; bblk < 8; bblk++) {
            f32x4 acc[4];
            #pragma unroll
            for (int jn = 0; jn < 4; jn++)
                acc[jn] = (f32x4){bi[jn].x, bi[jn].y, bi[jn].z, bi[jn].w};
            #pragma unroll
            for (int kk = 0; kk < 8; kk++) {
                f16x8 xb = *(const f16x8*)(&xt[bblk * 16 + l15][kk * 32 + quad * 8]);
                #pragma unroll
                for (int jn = 0; jn < 4; jn++)
                    acc[jn] = MF(wf[jn][kk], xb, acc[jn]);
            }
            #pragma unroll
            for (int jn = 0; jn < 4; jn++) {
                int j0 = w * 64 + jn * 16 + quad * 4;
                *(f32x4*)(preT + ((size_t)t * Bsz + bblk * 16 + l15) * Hn + j0) = acc[jn];
            }
        }
    }
}

// ---------------------------------------------------------------------------
// K2 (producer-consumer layer pipeline, 16 WGs x 512 thr). FENCE-FREE:
//   r4/r5 post-mortem: the consumer's per-step agent-ACQUIRE fence (vmcnt
//   drain + cache invalidate = a full coherence round trip, ~2000+cy) was the
//   2x regression, not the producer drain. It is unnecessary: h1 loads are
//   agent-scope (coherence-point) accesses, every address is read once per
//   launch, and reads are issued only after the flag proves the matching
//   stores retired (counted vmcnt + barrier precede the flag store).
//   Compiler ordering pinned with a zero-cost asm memory clobber; HW
//   ordering via the data-dependent spin branch.
//   Producer: per-step work only; every 8 steps `vmcnt(32)` (current chunk
//   of 8x4 VMEM ops may fly; all prior chunks retired) -> barrier ->
//   flag = retired-step count. Producer NEVER waits on the consumer.
//   Consumer: per-step relaxed flag check (no spin after warmup: producer
//   ~800cy/step < consumer ~1500cy/step), h1 double-buffered in registers,
//   prefetched one step ahead under the MFMAs.
// ---------------------------------------------------------------------------
__global__ __launch_bounds__(512, 1) void k_fused(
    const float* __restrict__ Whh0, const float* __restrict__ Wxh1,
    const float* __restrict__ Whh1, const float* __restrict__ b1v,
    const float* __restrict__ fcw,  const float* __restrict__ fcb,
    const float* __restrict__ preT, float* __restrict__ out)
{
    __shared__ __align__(16) f16 hbuf[2][4096];  // producer: h1; consumer: h2

    const int tid  = threadIdx.x;
    const int lane = tid & 63, l15 = lane & 15, quad = lane >> 4;
    const int w    = tid >> 6;
    const int colbase = w * 32;
    const int gidx = blockIdx.x & 7;
    const int bg   = gidx * 16;

    for (int i = tid; i < 8192; i += 512) ((f16*)hbuf)[i] = (f16)0.0f;

    int wroff[2];
    #pragma unroll
    for (int jn = 0; jn < 2; jn++) {
        int n0 = colbase + jn * 16 + quad * 4;
        wroff[jn] = (n0 >> 5) * 512 + ((n0 >> 3) & 3) * 128 + l15 * 8 + (n0 & 7);
    }

    unsigned long long* hg = g_h1 + (size_t)gidx * (1024 * 1024);
    int* flagp = &g_flag[gidx * 64];

    if (blockIdx.x < 8) {
        // ================= PRODUCER (layer 1) =================
        f16x8 wh0[2][8];
        #pragma unroll
        for (int jn = 0; jn < 2; jn++) {
            int j = colbase + jn * 16 + l15;
            #pragma unroll
            for (int kk = 0; kk < 8; kk++)
                #pragma unroll
                for (int e = 0; e < 8; e++)
                    wh0[jn][kk][e] = (f16)Whh0[(size_t)j * Hn + kk * 32 + quad * 8 + e];
        }
        const float* pp = preT + ((size_t)(bg + l15)) * Hn + colbase + quad * 4;
        f32x4 pnv0 = *(const f32x4*)(pp);
        f32x4 pnv1 = *(const f32x4*)(pp + 16);
        __syncthreads();

// Step I (parity P=I&1): read h1[I-1] from hbuf[P^1], write h1[I] to hbuf[P]
// + publish to g_h1. Exactly 4 VMEM/lane/step (2 loads, 2 stores), in order.
// No vmcnt waits in the steady step.
#define PSTEP(P, I, TF) { \
    f32x4 accA[2]; \
    accA[0] = pnv0; accA[1] = pnv1; \
    pnv0 = *(const f32x4*)(pp + (size_t)(TF) * (Bsz * Hn)); \
    pnv1 = *(const f32x4*)(pp + (size_t)(TF) * (Bsz * Hn) + 16); \
    _Pragma("unroll") for (int kk = 0; kk < 8; kk++) { \
        f16x8 hb = *(const f16x8*)(&hbuf[(P)^1][kk * 512 + lane * 8]); \
        accA[0] = MF(wh0[0][kk], hb, accA[0]); \
        accA[1] = MF(wh0[1][kk], hb, accA[1]); \
    } \
    _Pragma("unroll") for (int jn = 0; jn < 2; jn++) { \
        union { f16x4 v; unsigned long long u; } t1; \
        t1.v = (f16x4){ (f16)tanh_fast(accA[jn][0]), (f16)tanh_fast(accA[jn][1]), \
                        (f16)tanh_fast(accA[jn][2]), (f16)tanh_fast(accA[jn][3]) }; \
        *(f16x4*)(&hbuf[(P)][wroff[jn]]) = t1.v; \
        __hip_atomic_store(hg + (size_t)(I) * 1024 + (wroff[jn] >> 2), t1.u, \
                           __ATOMIC_RELAXED, __HIP_MEMORY_SCOPE_AGENT); \
    } \
    wg_barrier(); \
}
// Chunk-end step (I = 8c+7): before the barrier, vmcnt(32) leaves at most the
// current chunk's 32 VMEM ops in flight => chunks < c fully retired => after
// the barrier (every wave did its own vmcnt) publish flag = 8c = (I)-7.
#define PSTEP_PUB(P, I, TF) { \
    f32x4 accA[2]; \
    accA[0] = pnv0; accA[1] = pnv1; \
    pnv0 = *(const f32x4*)(pp + (size_t)(TF) * (Bsz * Hn)); \
    pnv1 = *(const f32x4*)(pp + (size_t)(TF) * (Bsz * Hn) + 16); \
    _Pragma("unroll") for (int kk = 0; kk < 8; kk++) { \
        f16x8 hb = *(const f16x8*)(&hbuf[(P)^1][kk * 512 + lane * 8]); \
        accA[0] = MF(wh0[0][kk], hb, accA[0]); \
        accA[1] = MF(wh0[1][kk], hb, accA[1]); \
    } \
    _Pragma("unroll") for (int jn = 0; jn < 2; jn++) { \
        union { f16x4 v; unsigned long long u; } t1; \
        t1.v = (f16x4){ (f16)tanh_fast(accA[jn][0]), (f16)tanh_fast(accA[jn][1]), \
                        (f16)tanh_fast(accA[jn][2]), (f16)tanh_fast(accA[jn][3]) }; \
        *(f16x4*)(&hbuf[(P)][wroff[jn]]) = t1.v; \
        __hip_atomic_store(hg + (size_t)(I) * 1024 + (wroff[jn] >> 2), t1.u, \
                           __ATOMIC_RELAXED, __HIP_MEMORY_SCOPE_AGENT); \
    } \
    asm volatile("s_waitcnt vmcnt(32)" ::: "memory"); \
    wg_barrier(); \
    if (tid == 0) \
        __hip_atomic_store(flagp, (I) - 7, __ATOMIC_RELAXED, __HIP_MEMORY_SCOPE_AGENT); \
}

        #pragma unroll 1
        for (int c = 0; c < 127; ++c) {
            const int t0 = c * 8;
            PSTEP(0, (t0 + 0), (t0 + 1))
            PSTEP(1, (t0 + 1), (t0 + 2))
            PSTEP(0, (t0 + 2), (t0 + 3))
            PSTEP(1, (t0 + 3), (t0 + 4))
            PSTEP(0, (t0 + 4), (t0 + 5))
            PSTEP(1, (t0 + 5), (t0 + 6))
            PSTEP(0, (t0 + 6), (t0 + 7))
            PSTEP_PUB(1, (t0 + 7), (t0 + 8))
        }
        // final chunk: steps 1016..1023 (last prefetch clamped)
        PSTEP(0, 1016, 1017)
        PSTEP(1, 1017, 1018)
        PSTEP(0, 1018, 1019)
        PSTEP(1, 1019, 1020)
        PSTEP(0, 1020, 1021)
        PSTEP(1, 1021, 1022)
        PSTEP(0, 1022, 1023)
        PSTEP(1, 1023, 1023)
#undef PSTEP
#undef PSTEP_PUB
        // epilogue: drain everything once, publish all 1024 steps
        asm volatile("s_waitcnt vmcnt(0)" ::: "memory");
        __syncthreads();
        if (tid == 0)
            __hip_atomic_store(flagp, 1024, __ATOMIC_RELAXED, __HIP_MEMORY_SCOPE_AGENT);
    } else {
        // ================= CONSUMER (layer 2 + head) =================
        f16x8 wx[2][8], wh1[2][8];
        #pragma unroll
        for (int jn = 0; jn < 2; jn++) {
            int j = colbase + jn * 16 + l15;
            #pragma unroll
            for (int kk = 0; kk < 8; kk++)
                #pragma unroll
                for (int e = 0; e < 8; e++) {
                    int o = (int)((size_t)j * Hn + kk * 32 + quad * 8 + e);
                    wx [jn][kk][e] = (f16)Wxh1[o];
                    wh1[jn][kk][e] = (f16)Whh1[o];
                }
        }
        float4 bi[2];
        #pragma unroll
        for (int jn = 0; jn < 2; jn++)
            bi[jn] = *(const float4*)(b1v + colbase + jn * 16 + quad * 4);
        __syncthreads();

        // startup: wait for h1[0] retired, load it into bufA. No HW fence:
        // agent-scope loads + read-once-fresh addresses + branch ordering.
        int fval = __hip_atomic_load(flagp, __ATOMIC_RELAXED, __HIP_MEMORY_SCOPE_AGENT);
        while (fval < 1) {
            __builtin_amdgcn_s_sleep(2);
            fval = __hip_atomic_load(flagp, __ATOMIC_RELAXED, __HIP_MEMORY_SCOPE_AGENT);
        }
        asm volatile("" ::: "memory");   // compiler: no loads above the spin
        f16x8 bufA[8], bufB[8];
        {
            unsigned long long* hp = hg + lane * 2;
            #pragma unroll
            for (int kk = 0; kk < 8; kk++) {
                union { unsigned long long u[2]; f16x8 v; } tb;
                tb.u[0] = __hip_atomic_load(hp + kk * 128,     __ATOMIC_RELAXED, __HIP_MEMORY_SCOPE_AGENT);
                tb.u[1] = __hip_atomic_load(hp + kk * 128 + 1, __ATOMIC_RELAXED, __HIP_MEMORY_SCOPE_AGENT);
                bufA[kk] = tb.v;
            }
        }
        fval = __hip_atomic_load(flagp, __ATOMIC_RELAXED, __HIP_MEMORY_SCOPE_AGENT);

// Step I (parity P=I&1): h2[I] = tanh(b1 + Wxh1.h1[I](CURB) + Whh1.h2[I-1]
// (hbuf[P])), write hbuf[P^1]. Prefetch h1[I+1] -> NXTB (requires flag >=
// I+2; fval is the one-step-stale prefetched flag; spin only if behind).
#define CSTEP(P, I, CURB, NXTB) { \
    int fchk = fval; \
    fval = __hip_atomic_load(flagp, __ATOMIC_RELAXED, __HIP_MEMORY_SCOPE_AGENT); \
    if (fchk < (I) + 2) { \
        do { __builtin_amdgcn_s_sleep(2); \
             fchk = __hip_atomic_load(flagp, __ATOMIC_RELAXED, __HIP_MEMORY_SCOPE_AGENT); \
        } while (fchk < (I) + 2); \
        fval = fchk; \
    } \
    asm volatile("" ::: "memory"); \
    { unsigned long long* hp = hg + (size_t)((I) + 1) * 1024 + lane * 2; \
      _Pragma("unroll") for (int kk = 0; kk < 8; kk++) { \
        union { unsigned long long u[2]; f16x8 v; } tb; \
        tb.u[0] = __hip_atomic_load(hp + kk * 128,     __ATOMIC_RELAXED, __HIP_MEMORY_SCOPE_AGENT); \
        tb.u[1] = __hip_atomic_load(hp + kk * 128 + 1, __ATOMIC_RELAXED, __HIP_MEMORY_SCOPE_AGENT); \
        NXTB[kk] = tb.v; } } \
    f32x4 accB[2]; \
    accB[0] = (f32x4){bi[0].x, bi[0].y, bi[0].z, bi[0].w}; \
    accB[1] = (f32x4){bi[1].x, bi[1].y, bi[1].z, bi[1].w}; \
    _Pragma("unroll") for (int kk = 0; kk < 8; kk++) { \
        f16x8 hb2 = *(const f16x8*)(&hbuf[(P)][kk * 512 + lane * 8]); \
        accB[0] = MF(wx [0][kk], CURB[kk], accB[0]); \
        accB[1] = MF(wx [1][kk], CURB[kk], accB[1]); \
        accB[0] = MF(wh1[0][kk], hb2, accB[0]); \
        accB[1] = MF(wh1[1][kk], hb2, accB[1]); \
    } \
    _Pragma("unroll") for (int jn = 0; jn < 2; jn++) { \
        f16x4 t2v = { (f16)tanh_fast(accB[jn][0]), (f16)tanh_fast(accB[jn][1]), \
                      (f16)tanh_fast(accB[jn][2]), (f16)tanh_fast(accB[jn][3]) }; \
        *(f16x4*)(&hbuf[(P)^1][wroff[jn]]) = t2v; \
    } \
    wg_barrier(); \
}
// Last step: no flag wait / no prefetch.
#define CSTEP_LAST(P, CURB) { \
    f32x4 accB[2]; \
    accB[0] = (f32x4){bi[0].x, bi[0].y, bi[0].z, bi[0].w}; \
    accB[1] = (f32x4){bi[1].x, bi[1].y, bi[1].z, bi[1].w}; \
    _Pragma("unroll") for (int kk = 0; kk < 8; kk++) { \
        f16x8 hb2 = *(const f16x8*)(&hbuf[(P)][kk * 512 + lane * 8]); \
        accB[0] = MF(wx [0][kk], CURB[kk], accB[0]); \
        accB[1] = MF(wx [1][kk], CURB[kk], accB[1]); \
        accB[0] = MF(wh1[0][kk], hb2, accB[0]); \
        accB[1] = MF(wh1[1][kk], hb2, accB[1]); \
    } \
    _Pragma("unroll") for (int jn = 0; jn < 2; jn++) { \
        f16x4 t2v = { (f16)tanh_fast(accB[jn][0]), (f16)tanh_fast(accB[jn][1]), \
                      (f16)tanh_fast(accB[jn][2]), (f16)tanh_fast(accB[jn][3]) }; \
        *(f16x4*)(&hbuf[(P)^1][wroff[jn]]) = t2v; \
    } \
    wg_barrier(); \
}

        #pragma unroll 1
        for (int tp = 0; tp < 511; ++tp) {
            const int t0 = 2 * tp;
            CSTEP(0, t0, bufA, bufB)
            CSTEP(1, (t0 + 1), bufB, bufA)
        }
        CSTEP(0, 1022, bufA, bufB)   // prefetches h1[1023], needs flag >= 1024
        CSTEP_LAST(1, bufB)          // i = 1023 -> writes hbuf[0]
#undef CSTEP
#undef CSTEP_LAST

        // head: final h2[1023] in hbuf[0]; frag-major.
        if (tid < 256) {
            const int bl = tid >> 4, o = (tid >> 3) & 1, kc = tid & 7;
            float s = 0.f;
            #pragma unroll
            for (int kq = 0; kq < 32; kq++) {
                int k = kc * 32 + kq;
                f16 hv = hbuf[0][(k >> 5) * 512 + ((k >> 3) & 3) * 128 + bl * 8 + (k & 7)];
                s += (float)hv * fcw[o * Hn + k];
            }
            s += __shfl_down(s, 4);
            s += __shfl_down(s, 2);
            s += __shfl_down(s, 1);
            if (kc == 0)
                out[(bg + bl) * 2 + o] = s + fcb[o];
        }

        // self-clean flags for the next launch / graph replay
        if (tid == 0)
            __hip_atomic_store(flagp, 0, __ATOMIC_RELAXED, __HIP_MEMORY_SCOPE_AGENT);
    }
}

extern "C" void kernel_launch(void* const* d_in, const int* in_sizes, int n_in,
                              void* d_out, int out_size, void* d_ws, size_t ws_size,
                              hipStream_t stream) {
    const float* x    = (const float*)d_in[0];
    const float* Wxh0 = (const float*)d_in[1];
    const float* Whh0 = (const float*)d_in[2];
    const float* b0   = (const float*)d_in[3];
    const float* Wxh1 = (const float*)d_in[4];
    const float* Whh1 = (const float*)d_in[5];
    const float* b1   = (const float*)d_in[6];
    const float* fcw  = (const float*)d_in[7];
    const float* fcb  = (const float*)d_in[8];
    float* out = (float*)d_out;

    float* preT = (float*)d_ws;  // pre[t][b][j] fp32 = 128 MiB

    k_xproj<<<dim3(256), dim3(256), 0, stream>>>(x, Wxh0, b0, preT);
    k_fused<<<dim3(16),  dim3(512), 0, stream>>>(Whh0, Wxh1, Whh1, b1,
                                                 fcw, fcb, preT, out);
}

// Round 7
// 1478.461 us; speedup vs baseline: 1.6526x; 1.1708x over previous
//
#include <hip/hip_runtime.h>

#define Bsz 128
#define Tn  1024
#define Dn  256
#define Hn  256
#define NXP 248   // xproj worker WGs (blockIdx 8..255)

typedef _Float16 f16;
typedef _Float16 f16x4 __attribute__((ext_vector_type(4)));
typedef _Float16 f16x8 __attribute__((ext_vector_type(8)));
typedef float f32x4 __attribute__((ext_vector_type(4)));
typedef unsigned long long u64;

#define MF(A, B, C) __builtin_amdgcn_mfma_f32_16x16x32_f16((A), (B), (C), 0, 0, 0)
#define ALOAD(p)     __hip_atomic_load((p),      __ATOMIC_RELAXED, __HIP_MEMORY_SCOPE_AGENT)
#define ASTORE(p, v) __hip_atomic_store((p), (v), __ATOMIC_RELAXED, __HIP_MEMORY_SCOPE_AGENT)

// Per-t readiness flags for pre[t] (set by xproj workers after their agent
// stores retire; consumed by the 8 recurrent WGs). Self-cleaning: the LAST
// recurrent WG (g_done counter) resets them -> correct across graph replays.
__device__ int g_pflag[1032];
__device__ int g_done;

// Exact tanh: 1 - 2/(e^{2x}+1) via v_exp_f32. err ~1e-6, saturates correctly.
__device__ __forceinline__ float tanh_fast(float x) {
    float e = __builtin_amdgcn_exp2f(x * 2.88539008177793f);  // e^{2x}
    return 1.0f - 2.0f * __builtin_amdgcn_rcpf(e + 1.0f);
}

// LDS-only barrier (lgkmcnt drain, no vmcnt): global loads/stores stay in
// flight across steps (pre prefetch latency is hidden across the barrier).
__device__ __forceinline__ void wg_barrier() {
    asm volatile("s_waitcnt lgkmcnt(0)\n\ts_barrier" ::: "memory");
}

// h fragment-major layout: element (m=batch 0..15, k=0..255) lives at
// f16 offset (k>>5)*512 + ((k>>3)&3)*128 + m*8 + (k&7).
// A wave's B-fragment read for K-block kk is 16B at kk*512 + lane*8
// -> stride-1 lane-contiguous, conflict-free.

// ---------------------------------------------------------------------------
// ONE kernel, 256 WGs x 512 thr:
//  blocks 0..7   : R3's proven single-WG recurrent loop (both layers + head,
//                  1 barrier/step) for b-group g = blockIdx; pre[t] loads are
//                  agent u64 loads gated by g_pflag[t] (1-step prefetched;
//                  never spins after the ~65us warmup).
//  blocks 8..255 : xproj workers. Worker w2 computes pre[t][b][j] for
//                  t = w2, w2+248, ... (round-robin => t=0..247 finish first).
//                  Publishes per t: agent u64 stores -> vmcnt(0) -> barrier ->
//                  g_pflag[t]=1 (relaxed; ordering via counted drain+barrier).
// Deadlock-free: workers never wait; consumers spin only on flags that
// workers set unconditionally.
// ---------------------------------------------------------------------------
__global__ __launch_bounds__(512, 1) void k_all(
    const float* __restrict__ x,    const float* __restrict__ Wxh0,
    const float* __restrict__ b0v,  const float* __restrict__ Whh0,
    const float* __restrict__ Wxh1, const float* __restrict__ Whh1,
    const float* __restrict__ b1v,  const float* __restrict__ fcw,
    const float* __restrict__ fcb,  float* __restrict__ preT,
    float* __restrict__ out)
{
    __shared__ __align__(16) f16 smem[128 * 264];  // 67.6 KB, carved per role
    __shared__ int sflag;

    const int tid  = threadIdx.x;
    const int lane = tid & 63, l15 = lane & 15, quad = lane >> 4;
    const int w    = tid >> 6;
    const int colbase = w * 32;

    if (blockIdx.x >= 8) {
        // ===================== XPROJ WORKER =====================
        f16 (*xt)[264] = (f16(*)[264])smem;
        const int w2 = blockIdx.x - 8;

        // A-fragments of Wxh0 (j = colbase + jn*16 + l15), vectorized
        f16x8 wf[2][8];
        #pragma unroll
        for (int jn = 0; jn < 2; jn++) {
            int j = colbase + jn * 16 + l15;
            #pragma unroll
            for (int kk = 0; kk < 8; kk++) {
                const float* wp = Wxh0 + (size_t)j * Dn + kk * 32 + quad * 8;
                float4 a = *(const float4*)(wp);
                float4 b = *(const float4*)(wp + 4);
                wf[jn][kk] = (f16x8){ (f16)a.x, (f16)a.y, (f16)a.z, (f16)a.w,
                                      (f16)b.x, (f16)b.y, (f16)b.z, (f16)b.w };
            }
        }
        float4 bx[2];
        #pragma unroll
        for (int jn = 0; jn < 2; jn++)
            bx[jn] = *(const float4*)(b0v + colbase + jn * 16 + quad * 4);

        #pragma unroll 1
        for (int t = w2; t < Tn; t += NXP) {
            // stage x[:, t, :] -> f16 LDS (row-major, padded)
            for (int i = tid; i < 128 * 64; i += 512) {
                int row = i >> 6, c4 = i & 63;
                float4 v = *(const float4*)(x + ((size_t)row * Tn + t) * Dn + c4 * 4);
                f16x4 tv = { (f16)v.x, (f16)v.y, (f16)v.z, (f16)v.w };
                *(f16x4*)(&xt[row][c4 * 4]) = tv;
            }
            __syncthreads();

            #pragma unroll 1
            for (int bblk = 0; bblk < 8; bblk++) {
                f32x4 acc[2];
                #pragma unroll
                for (int jn = 0; jn < 2; jn++)
                    acc[jn] = (f32x4){bx[jn].x, bx[jn].y, bx[jn].z, bx[jn].w};
                #pragma unroll
                for (int kk = 0; kk < 8; kk++) {
                    f16x8 xb = *(const f16x8*)(&xt[bblk * 16 + l15][kk * 32 + quad * 8]);
                    acc[0] = MF(wf[0][kk], xb, acc[0]);
                    acc[1] = MF(wf[1][kk], xb, acc[1]);
                }
                // pre[t][b][j]: agent stores (must reach the coherence point
                // -- consumers on other XCDs read it there)
                #pragma unroll
                for (int jn = 0; jn < 2; jn++) {
                    int j0 = colbase + jn * 16 + quad * 4;
                    union { f32x4 v; u64 u[2]; } cv; cv.v = acc[jn];
                    size_t fi = ((size_t)t * Bsz + bblk * 16 + l15) * Hn + j0;
                    ASTORE((u64*)preT + (fi >> 1),     cv.u[0]);
                    ASTORE((u64*)preT + (fi >> 1) + 1, cv.u[1]);
                }
            }
            // retire this t's stores, then publish
            asm volatile("s_waitcnt vmcnt(0)" ::: "memory");
            __syncthreads();
            if (tid == 0) ASTORE(&g_pflag[t], 1);
        }
        return;
    }

    // ===================== RECURRENT (R3 skeleton) =====================
    f16* h1f0 = smem;
    f16* h1f1 = smem + 4096;
    f16* h2f0 = smem + 8192;
    f16* h2f1 = smem + 12288;
    const int bg = blockIdx.x * 16;

    for (int i = tid; i < 16384; i += 512) smem[i] = (f16)0.0f;

    // weight A-fragments (vectorized loads): row j = colbase + jn*16 + l15
    f16x8 wh0[2][8], wx[2][8], wh1[2][8];
    #pragma unroll
    for (int jn = 0; jn < 2; jn++) {
        int j = colbase + jn * 16 + l15;
        #pragma unroll
        for (int kk = 0; kk < 8; kk++) {
            size_t o = (size_t)j * Hn + kk * 32 + quad * 8;
            float4 a, b;
            a = *(const float4*)(Whh0 + o); b = *(const float4*)(Whh0 + o + 4);
            wh0[jn][kk] = (f16x8){ (f16)a.x, (f16)a.y, (f16)a.z, (f16)a.w,
                                   (f16)b.x, (f16)b.y, (f16)b.z, (f16)b.w };
            a = *(const float4*)(Wxh1 + o); b = *(const float4*)(Wxh1 + o + 4);
            wx[jn][kk]  = (f16x8){ (f16)a.x, (f16)a.y, (f16)a.z, (f16)a.w,
                                   (f16)b.x, (f16)b.y, (f16)b.z, (f16)b.w };
            a = *(const float4*)(Whh1 + o); b = *(const float4*)(Whh1 + o + 4);
            wh1[jn][kk] = (f16x8){ (f16)a.x, (f16)a.y, (f16)a.z, (f16)a.w,
                                   (f16)b.x, (f16)b.y, (f16)b.z, (f16)b.w };
        }
    }
    float4 bi[2];
    #pragma unroll
    for (int jn = 0; jn < 2; jn++)
        bi[jn] = *(const float4*)(b1v + colbase + jn * 16 + quad * 4);

    int wroff[2];
    #pragma unroll
    for (int jn = 0; jn < 2; jn++) {
        int n0 = colbase + jn * 16 + quad * 4;
        wroff[jn] = (n0 >> 5) * 512 + ((n0 >> 3) & 3) * 128 + l15 * 8 + (n0 & 7);
    }

    // pre[t][bg+l15][colbase + jn*16 + quad*4 + r] as u64 pairs
    const u64* ppu = (const u64*)preT +
                     ((((size_t)(bg + l15)) * Hn + colbase + quad * 4) >> 1);

    // startup: wait for pre[0], load it; prefetch flag for pre[1]
    int fval = ALOAD(&g_pflag[0]);
    while (fval < 1) { __builtin_amdgcn_s_sleep(8); fval = ALOAD(&g_pflag[0]); }
    asm volatile("" ::: "memory");
    u64 pnu0 = ALOAD(ppu),     pnu1 = ALOAD(ppu + 1);
    u64 pnu2 = ALOAD(ppu + 8), pnu3 = ALOAD(ppu + 9);
    fval = ALOAD(&g_pflag[1]);
    __syncthreads();

// accA <- pre[t] currently in pnu (xproj already added b0)
#define UNPACK_ACCA \
    f32x4 accA[2]; \
    { union { u64 u[2]; f32x4 v; } c0, c1; \
      c0.u[0] = pnu0; c0.u[1] = pnu1; c1.u[0] = pnu2; c1.u[1] = pnu3; \
      accA[0] = c0.v; accA[1] = c1.v; }

// check flag for pre[I+1] (fval = prefetched g_pflag[I+1]); prefetch
// pre[I+1] into pnu and g_pflag[I+2] into fval. Spin only if behind
// (never after warmup: xproj per-t rate >> consumer step rate).
#define PREFETCH(I) { \
    int fnew = ALOAD(&g_pflag[(I) + 2]); \
    if (fval < 1) { \
        do { __builtin_amdgcn_s_sleep(2); fval = ALOAD(&g_pflag[(I) + 1]); } \
        while (fval < 1); \
    } \
    asm volatile("" ::: "memory"); \
    const u64* pq = ppu + (size_t)((I) + 1) * ((Bsz * Hn) >> 1); \
    pnu0 = ALOAD(pq);     pnu1 = ALOAD(pq + 1); \
    pnu2 = ALOAD(pq + 8); pnu3 = ALOAD(pq + 9); \
    fval = fnew; }

// One R3 step: h1[I] = tanh(pre[I] + Whh0.h1[I-1] (H1R)) -> H1W;
//              h2[I-1] = tanh(b1 + Wxh1.h1[I-1] (hb1) + Whh1.h2[I-2] (H2R))
//              -> H2W. h1 tail between the MFMA blocks (schedules into the
//              accB shadow). ONE barrier.
#define FSTEP(H1R, H1W, H2R, H2W, I) { \
    UNPACK_ACCA \
    PREFETCH(I) \
    f16x8 hb1[8]; \
    _Pragma("unroll") for (int kk = 0; kk < 8; kk++) { \
        hb1[kk] = *(const f16x8*)((H1R) + kk * 512 + lane * 8); \
        accA[0] = MF(wh0[0][kk], hb1[kk], accA[0]); \
        accA[1] = MF(wh0[1][kk], hb1[kk], accA[1]); \
    } \
    _Pragma("unroll") for (int jn = 0; jn < 2; jn++) { \
        f16x4 t1v = { (f16)tanh_fast(accA[jn][0]), (f16)tanh_fast(accA[jn][1]), \
                      (f16)tanh_fast(accA[jn][2]), (f16)tanh_fast(accA[jn][3]) }; \
        *(f16x4*)((H1W) + wroff[jn]) = t1v; \
    } \
    f32x4 accB[2]; \
    accB[0] = (f32x4){bi[0].x, bi[0].y, bi[0].z, bi[0].w}; \
    accB[1] = (f32x4){bi[1].x, bi[1].y, bi[1].z, bi[1].w}; \
    _Pragma("unroll") for (int kk = 0; kk < 8; kk++) { \
        f16x8 hb2 = *(const f16x8*)((H2R) + kk * 512 + lane * 8); \
        accB[0] = MF(wx [0][kk], hb1[kk], accB[0]); \
        accB[1] = MF(wx [1][kk], hb1[kk], accB[1]); \
        accB[0] = MF(wh1[0][kk], hb2, accB[0]); \
        accB[1] = MF(wh1[1][kk], hb2, accB[1]); \
    } \
    _Pragma("unroll") for (int jn = 0; jn < 2; jn++) { \
        f16x4 t2v = { (f16)tanh_fast(accB[jn][0]), (f16)tanh_fast(accB[jn][1]), \
                      (f16)tanh_fast(accB[jn][2]), (f16)tanh_fast(accB[jn][3]) }; \
        *(f16x4*)((H2W) + wroff[jn]) = t2v; \
    } \
    wg_barrier(); \
}

// Last full step (I = 1023): pnu already holds pre[1023]; no flag/prefetch.
#define FSTEP_LAST(H1R, H1W, H2R, H2W) { \
    UNPACK_ACCA \
    f16x8 hb1[8]; \
    _Pragma("unroll") for (int kk = 0; kk < 8; kk++) { \
        hb1[kk] = *(const f16x8*)((H1R) + kk * 512 + lane * 8); \
        accA[0] = MF(wh0[0][kk], hb1[kk], accA[0]); \
        accA[1] = MF(wh0[1][kk], hb1[kk], accA[1]); \
    } \
    _Pragma("unroll") for (int jn = 0; jn < 2; jn++) { \
        f16x4 t1v = { (f16)tanh_fast(accA[jn][0]), (f16)tanh_fast(accA[jn][1]), \
                      (f16)tanh_fast(accA[jn][2]), (f16)tanh_fast(accA[jn][3]) }; \
        *(f16x4*)((H1W) + wroff[jn]) = t1v; \
    } \
    f32x4 accB[2]; \
    accB[0] = (f32x4){bi[0].x, bi[0].y, bi[0].z, bi[0].w}; \
    accB[1] = (f32x4){bi[1].x, bi[1].y, bi[1].z, bi[1].w}; \
    _Pragma("unroll") for (int kk = 0; kk < 8; kk++) { \
        f16x8 hb2 = *(const f16x8*)((H2R) + kk * 512 + lane * 8); \
        accB[0] = MF(wx [0][kk], hb1[kk], accB[0]); \
        accB[1] = MF(wx [1][kk], hb1[kk], accB[1]); \
        accB[0] = MF(wh1[0][kk], hb2, accB[0]); \
        accB[1] = MF(wh1[1][kk], hb2, accB[1]); \
    } \
    _Pragma("unroll") for (int jn = 0; jn < 2; jn++) { \
        f16x4 t2v = { (f16)tanh_fast(accB[jn][0]), (f16)tanh_fast(accB[jn][1]), \
                      (f16)tanh_fast(accB[jn][2]), (f16)tanh_fast(accB[jn][3]) }; \
        *(f16x4*)((H2W) + wroff[jn]) = t2v; \
    } \
    wg_barrier(); \
}

    // --- peeled i = 0: h1[0] only (h2[-1] stays zero) ---
    {
        UNPACK_ACCA
        PREFETCH(0)
        #pragma unroll
        for (int kk = 0; kk < 8; kk++) {
            f16x8 hb = *(const f16x8*)(h1f1 + kk * 512 + lane * 8);  // zeros
            accA[0] = MF(wh0[0][kk], hb, accA[0]);
            accA[1] = MF(wh0[1][kk], hb, accA[1]);
        }
        #pragma unroll
        for (int jn = 0; jn < 2; jn++) {
            f16x4 t1v = { (f16)tanh_fast(accA[jn][0]), (f16)tanh_fast(accA[jn][1]),
                          (f16)tanh_fast(accA[jn][2]), (f16)tanh_fast(accA[jn][3]) };
            *(f16x4*)(h1f0 + wroff[jn]) = t1v;
        }
        wg_barrier();
    }

    // --- steady state: i = 1..1022 ---
    #pragma unroll 1
    for (int tp = 0; tp < 511; ++tp) {
        FSTEP(h1f0, h1f1, h2f1, h2f0, (2 * tp + 1))
        FSTEP(h1f1, h1f0, h2f0, h2f1, (2 * tp + 2))
    }
    // --- i = 1023 ---
    FSTEP_LAST(h1f0, h1f1, h2f1, h2f0)
#undef FSTEP
#undef FSTEP_LAST
#undef PREFETCH
#undef UNPACK_ACCA

    // --- peeled i = 1024: h2[1023] = tanh(b1 + Wxh1.h1[1023] + Whh1.h2[1022])
    {
        f32x4 accB[2];
        accB[0] = (f32x4){bi[0].x, bi[0].y, bi[0].z, bi[0].w};
        accB[1] = (f32x4){bi[1].x, bi[1].y, bi[1].z, bi[1].w};
        #pragma unroll
        for (int kk = 0; kk < 8; kk++) {
            f16x8 hb1 = *(const f16x8*)(h1f1 + kk * 512 + lane * 8);  // h1[1023]
            f16x8 hb2 = *(const f16x8*)(h2f0 + kk * 512 + lane * 8);  // h2[1022]
            accB[0] = MF(wx [0][kk], hb1, accB[0]);
            accB[1] = MF(wx [1][kk], hb1, accB[1]);
            accB[0] = MF(wh1[0][kk], hb2, accB[0]);
            accB[1] = MF(wh1[1][kk], hb2, accB[1]);
        }
        #pragma unroll
        for (int jn = 0; jn < 2; jn++) {
            f16x4 t2v = { (f16)tanh_fast(accB[jn][0]), (f16)tanh_fast(accB[jn][1]),
                          (f16)tanh_fast(accB[jn][2]), (f16)tanh_fast(accB[jn][3]) };
            *(f16x4*)(h2f1 + wroff[jn]) = t2v;
        }
        wg_barrier();
    }

    // head: final h2[1023] in h2f1; frag-major.
    if (tid < 256) {
        const int bl = tid >> 4, o = (tid >> 3) & 1, kc = tid & 7;
        float s = 0.f;
        #pragma unroll
        for (int kq = 0; kq < 32; kq++) {
            int k = kc * 32 + kq;
            f16 hv = h2f1[(k >> 5) * 512 + ((k >> 3) & 3) * 128 + bl * 8 + (k & 7)];
            s += (float)hv * fcw[o * Hn + k];
        }
        s += __shfl_down(s, 4);
        s += __shfl_down(s, 2);
        s += __shfl_down(s, 1);
        if (kc == 0)
            out[(bg + bl) * 2 + o] = s + fcb[o];
    }

    // flag self-clean: LAST of the 8 recurrent WGs (all consumers provably
    // done) resets g_pflag + g_done for the next launch / graph replay.
    __syncthreads();
    if (tid == 0) {
        int old = atomicAdd(&g_done, 1);
        sflag = (old == 7) ? 1 : 0;
    }
    __syncthreads();
    if (sflag) {
        for (int i = tid; i < 1032; i += 512) ASTORE(&g_pflag[i], 0);
        if (tid == 0) ASTORE(&g_done, 0);
    }
}

extern "C" void kernel_launch(void* const* d_in, const int* in_sizes, int n_in,
                              void* d_out, int out_size, void* d_ws, size_t ws_size,
                              hipStream_t stream) {
    const float* x    = (const float*)d_in[0];
    const float* Wxh0 = (const float*)d_in[1];
    const float* Whh0 = (const float*)d_in[2];
    const float* b0   = (const float*)d_in[3];
    const float* Wxh1 = (const float*)d_in[4];
    const float* Whh1 = (const float*)d_in[5];
    const float* b1   = (const float*)d_in[6];
    const float* fcw  = (const float*)d_in[7];
    const float* fcb  = (const float*)d_in[8];
    float* out = (float*)d_out;

    float* preT = (float*)d_ws;  // pre[t][b][j] fp32 = 128 MiB

    k_all<<<dim3(256), dim3(512), 0, stream>>>(x, Wxh0, b0, Whh0, Wxh1, Whh1,
                                               b1, fcw, fcb, preT, out);
}

// Round 8
// 1473.441 us; speedup vs baseline: 1.6582x; 1.0034x over previous
//
#include <hip/hip_runtime.h>

#define Bsz 128
#define Tn  1024
#define Dn  256
#define Hn  256
#define NXP 248   // xproj worker WGs (blockIdx 8..255)

typedef _Float16 f16;
typedef _Float16 f16x4 __attribute__((ext_vector_type(4)));
typedef _Float16 f16x8 __attribute__((ext_vector_type(8)));
typedef float f32x4 __attribute__((ext_vector_type(4)));
typedef unsigned long long u64;

#define MF(A, B, C) __builtin_amdgcn_mfma_f32_16x16x32_f16((A), (B), (C), 0, 0, 0)
#define ALOAD(p)     __hip_atomic_load((p),      __ATOMIC_RELAXED, __HIP_MEMORY_SCOPE_AGENT)
#define ASTORE(p, v) __hip_atomic_store((p), (v), __ATOMIC_RELAXED, __HIP_MEMORY_SCOPE_AGENT)

// Per-t readiness flags for pre[t] (set by xproj workers after their agent
// stores retire; consumed by the 8 recurrent WGs). Self-cleaning: the LAST
// recurrent WG (g_done counter) resets them -> correct across graph replays.
__device__ int g_pflag[1032];
__device__ int g_done;

// Exact tanh: 1 - 2/(e^{2x}+1) via v_exp_f32. err ~1e-6, saturates correctly.
__device__ __forceinline__ float tanh_fast(float x) {
    float e = __builtin_amdgcn_exp2f(x * 2.88539008177793f);  // e^{2x}
    return 1.0f - 2.0f * __builtin_amdgcn_rcpf(e + 1.0f);
}

// LDS-only barrier (lgkmcnt drain, no vmcnt): global loads/stores stay in
// flight across steps (pre prefetch latency is hidden across the barrier).
__device__ __forceinline__ void wg_barrier() {
    asm volatile("s_waitcnt lgkmcnt(0)\n\ts_barrier" ::: "memory");
}

// h fragment-major layout: element (m=batch 0..15, k=0..255) lives at
// f16 offset (k>>5)*512 + ((k>>3)&3)*128 + m*8 + (k&7).
// A wave's B-fragment read for K-block kk is 16B at kk*512 + lane*8
// -> stride-1 lane-contiguous, conflict-free.

// ---------------------------------------------------------------------------
// ONE kernel, 256 WGs x 512 thr:
//  blocks 0..7   : R3's proven single-WG recurrent loop (both layers + head,
//                  1 barrier/step) for b-group g = blockIdx; pre[t] loads are
//                  agent u64 loads gated by g_pflag[t] (1-step prefetched).
//  blocks 8..255 : xproj workers, NO LDS STAGING (r7 post-mortem: the
//                  load->ds_write staging chain serialized HBM latency ->
//                  ~60us/t; register-direct x fragments pipeline ~128
//                  independent loads -> ~2-3us/t, overlap window ~25us).
//  LDS statically padded to 84 KB => 1 WG/CU: workers never co-reside with
//  recurrent WGs (MFMA/LDS/issue isolation).
// Deadlock-free: workers never wait; consumers spin only on flags that
// workers set unconditionally.
// ---------------------------------------------------------------------------
__global__ __launch_bounds__(512, 1) void k_all(
    const float* __restrict__ x,    const float* __restrict__ Wxh0,
    const float* __restrict__ b0v,  const float* __restrict__ Whh0,
    const float* __restrict__ Wxh1, const float* __restrict__ Whh1,
    const float* __restrict__ b1v,  const float* __restrict__ fcw,
    const float* __restrict__ fcb,  float* __restrict__ preT,
    float* __restrict__ out)
{
    __shared__ __align__(16) f16 smem[43008];  // 84 KB: forces 1 WG/CU
    __shared__ int sflag;

    const int tid  = threadIdx.x;
    const int lane = tid & 63, l15 = lane & 15, quad = lane >> 4;
    const int w    = tid >> 6;
    const int colbase = w * 32;

    if (blockIdx.x >= 8) {
        // ===================== XPROJ WORKER (register-direct) ==============
        const int w2 = blockIdx.x - 8;

        // A-fragments of Wxh0 (j = colbase + jn*16 + l15), vectorized
        f16x8 wf[2][8];
        #pragma unroll
        for (int jn = 0; jn < 2; jn++) {
            int j = colbase + jn * 16 + l15;
            #pragma unroll
            for (int kk = 0; kk < 8; kk++) {
                const float* wp = Wxh0 + (size_t)j * Dn + kk * 32 + quad * 8;
                float4 a = *(const float4*)(wp);
                float4 b = *(const float4*)(wp + 4);
                wf[jn][kk] = (f16x8){ (f16)a.x, (f16)a.y, (f16)a.z, (f16)a.w,
                                      (f16)b.x, (f16)b.y, (f16)b.z, (f16)b.w };
            }
        }
        float4 bx[2];
        #pragma unroll
        for (int jn = 0; jn < 2; jn++)
            bx[jn] = *(const float4*)(b0v + colbase + jn * 16 + quad * 4);

        #pragma unroll 1
        for (int t = w2; t < Tn; t += NXP) {
            // B-fragments of x_t straight from global: lane (quad,l15) at
            // (bblk,kk) needs x[bblk*16+l15][t][kk*32+quad*8 .. +7].
            #pragma unroll
            for (int bblk = 0; bblk < 8; bblk++) {
                const float* xp = x + ((size_t)(bblk * 16 + l15) * Tn + t) * Dn + quad * 8;
                f16x8 xb[8];
                #pragma unroll
                for (int kk = 0; kk < 8; kk++) {
                    float4 a = *(const float4*)(xp + kk * 32);
                    float4 b = *(const float4*)(xp + kk * 32 + 4);
                    xb[kk] = (f16x8){ (f16)a.x, (f16)a.y, (f16)a.z, (f16)a.w,
                                      (f16)b.x, (f16)b.y, (f16)b.z, (f16)b.w };
                }
                f32x4 acc0 = (f32x4){bx[0].x, bx[0].y, bx[0].z, bx[0].w};
                f32x4 acc1 = (f32x4){bx[1].x, bx[1].y, bx[1].z, bx[1].w};
                #pragma unroll
                for (int kk = 0; kk < 8; kk++) {
                    acc0 = MF(wf[0][kk], xb[kk], acc0);
                    acc1 = MF(wf[1][kk], xb[kk], acc1);
                }
                // pre[t][b][j]: agent stores (consumers on other XCDs read at
                // the coherence point)
                size_t fi0 = ((size_t)t * Bsz + bblk * 16 + l15) * Hn + colbase + quad * 4;
                union { f32x4 v; u64 u[2]; } c0; c0.v = acc0;
                ASTORE((u64*)preT + (fi0 >> 1),     c0.u[0]);
                ASTORE((u64*)preT + (fi0 >> 1) + 1, c0.u[1]);
                union { f32x4 v; u64 u[2]; } c1; c1.v = acc1;
                ASTORE((u64*)preT + (fi0 >> 1) + 8, c1.u[0]);
                ASTORE((u64*)preT + (fi0 >> 1) + 9, c1.u[1]);
            }
            // retire this t's stores, then publish
            asm volatile("s_waitcnt vmcnt(0)" ::: "memory");
            __syncthreads();
            if (tid == 0) ASTORE(&g_pflag[t], 1);
        }
        return;
    }

    // ===================== RECURRENT (R3 skeleton, unchanged) ==============
    f16* h1f0 = smem;
    f16* h1f1 = smem + 4096;
    f16* h2f0 = smem + 8192;
    f16* h2f1 = smem + 12288;
    const int bg = blockIdx.x * 16;

    for (int i = tid; i < 16384; i += 512) smem[i] = (f16)0.0f;

    // weight A-fragments (vectorized loads): row j = colbase + jn*16 + l15
    f16x8 wh0[2][8], wx[2][8], wh1[2][8];
    #pragma unroll
    for (int jn = 0; jn < 2; jn++) {
        int j = colbase + jn * 16 + l15;
        #pragma unroll
        for (int kk = 0; kk < 8; kk++) {
            size_t o = (size_t)j * Hn + kk * 32 + quad * 8;
            float4 a, b;
            a = *(const float4*)(Whh0 + o); b = *(const float4*)(Whh0 + o + 4);
            wh0[jn][kk] = (f16x8){ (f16)a.x, (f16)a.y, (f16)a.z, (f16)a.w,
                                   (f16)b.x, (f16)b.y, (f16)b.z, (f16)b.w };
            a = *(const float4*)(Wxh1 + o); b = *(const float4*)(Wxh1 + o + 4);
            wx[jn][kk]  = (f16x8){ (f16)a.x, (f16)a.y, (f16)a.z, (f16)a.w,
                                   (f16)b.x, (f16)b.y, (f16)b.z, (f16)b.w };
            a = *(const float4*)(Whh1 + o); b = *(const float4*)(Whh1 + o + 4);
            wh1[jn][kk] = (f16x8){ (f16)a.x, (f16)a.y, (f16)a.z, (f16)a.w,
                                   (f16)b.x, (f16)b.y, (f16)b.z, (f16)b.w };
        }
    }
    float4 bi[2];
    #pragma unroll
    for (int jn = 0; jn < 2; jn++)
        bi[jn] = *(const float4*)(b1v + colbase + jn * 16 + quad * 4);

    int wroff[2];
    #pragma unroll
    for (int jn = 0; jn < 2; jn++) {
        int n0 = colbase + jn * 16 + quad * 4;
        wroff[jn] = (n0 >> 5) * 512 + ((n0 >> 3) & 3) * 128 + l15 * 8 + (n0 & 7);
    }

    // pre[t][bg+l15][colbase + jn*16 + quad*4 + r] as u64 pairs
    const u64* ppu = (const u64*)preT +
                     ((((size_t)(bg + l15)) * Hn + colbase + quad * 4) >> 1);

    // startup: wait for pre[0], load it; prefetch flag for pre[1]
    int fval = ALOAD(&g_pflag[0]);
    while (fval < 1) { __builtin_amdgcn_s_sleep(8); fval = ALOAD(&g_pflag[0]); }
    asm volatile("" ::: "memory");
    u64 pnu0 = ALOAD(ppu),     pnu1 = ALOAD(ppu + 1);
    u64 pnu2 = ALOAD(ppu + 8), pnu3 = ALOAD(ppu + 9);
    fval = ALOAD(&g_pflag[1]);
    __syncthreads();

// accA <- pre[t] currently in pnu (xproj already added b0)
#define UNPACK_ACCA \
    f32x4 accA[2]; \
    { union { u64 u[2]; f32x4 v; } c0, c1; \
      c0.u[0] = pnu0; c0.u[1] = pnu1; c1.u[0] = pnu2; c1.u[1] = pnu3; \
      accA[0] = c0.v; accA[1] = c1.v; }

// check flag for pre[I+1] (fval = prefetched g_pflag[I+1]); prefetch
// pre[I+1] into pnu and g_pflag[I+2] into fval. Spin only if behind.
#define PREFETCH(I) { \
    int fnew = ALOAD(&g_pflag[(I) + 2]); \
    if (fval < 1) { \
        do { __builtin_amdgcn_s_sleep(2); fval = ALOAD(&g_pflag[(I) + 1]); } \
        while (fval < 1); \
    } \
    asm volatile("" ::: "memory"); \
    const u64* pq = ppu + (size_t)((I) + 1) * ((Bsz * Hn) >> 1); \
    pnu0 = ALOAD(pq);     pnu1 = ALOAD(pq + 1); \
    pnu2 = ALOAD(pq + 8); pnu3 = ALOAD(pq + 9); \
    fval = fnew; }

// One R3 step: h1[I] = tanh(pre[I] + Whh0.h1[I-1] (H1R)) -> H1W;
//              h2[I-1] = tanh(b1 + Wxh1.h1[I-1] (hb1) + Whh1.h2[I-2] (H2R))
//              -> H2W. h1 tail between the MFMA blocks (schedules into the
//              accB shadow). ONE barrier.
#define FSTEP(H1R, H1W, H2R, H2W, I) { \
    UNPACK_ACCA \
    PREFETCH(I) \
    f16x8 hb1[8]; \
    _Pragma("unroll") for (int kk = 0; kk < 8; kk++) { \
        hb1[kk] = *(const f16x8*)((H1R) + kk * 512 + lane * 8); \
        accA[0] = MF(wh0[0][kk], hb1[kk], accA[0]); \
        accA[1] = MF(wh0[1][kk], hb1[kk], accA[1]); \
    } \
    _Pragma("unroll") for (int jn = 0; jn < 2; jn++) { \
        f16x4 t1v = { (f16)tanh_fast(accA[jn][0]), (f16)tanh_fast(accA[jn][1]), \
                      (f16)tanh_fast(accA[jn][2]), (f16)tanh_fast(accA[jn][3]) }; \
        *(f16x4*)((H1W) + wroff[jn]) = t1v; \
    } \
    f32x4 accB[2]; \
    accB[0] = (f32x4){bi[0].x, bi[0].y, bi[0].z, bi[0].w}; \
    accB[1] = (f32x4){bi[1].x, bi[1].y, bi[1].z, bi[1].w}; \
    _Pragma("unroll") for (int kk = 0; kk < 8; kk++) { \
        f16x8 hb2 = *(const f16x8*)((H2R) + kk * 512 + lane * 8); \
        accB[0] = MF(wx [0][kk], hb1[kk], accB[0]); \
        accB[1] = MF(wx [1][kk], hb1[kk], accB[1]); \
        accB[0] = MF(wh1[0][kk], hb2, accB[0]); \
        accB[1] = MF(wh1[1][kk], hb2, accB[1]); \
    } \
    _Pragma("unroll") for (int jn = 0; jn < 2; jn++) { \
        f16x4 t2v = { (f16)tanh_fast(accB[jn][0]), (f16)tanh_fast(accB[jn][1]), \
                      (f16)tanh_fast(accB[jn][2]), (f16)tanh_fast(accB[jn][3]) }; \
        *(f16x4*)((H2W) + wroff[jn]) = t2v; \
    } \
    wg_barrier(); \
}

// Last full step (I = 1023): pnu already holds pre[1023]; no flag/prefetch.
#define FSTEP_LAST(H1R, H1W, H2R, H2W) { \
    UNPACK_ACCA \
    f16x8 hb1[8]; \
    _Pragma("unroll") for (int kk = 0; kk < 8; kk++) { \
        hb1[kk] = *(const f16x8*)((H1R) + kk * 512 + lane * 8); \
        accA[0] = MF(wh0[0][kk], hb1[kk], accA[0]); \
        accA[1] = MF(wh0[1][kk], hb1[kk], accA[1]); \
    } \
    _Pragma("unroll") for (int jn = 0; jn < 2; jn++) { \
        f16x4 t1v = { (f16)tanh_fast(accA[jn][0]), (f16)tanh_fast(accA[jn][1]), \
                      (f16)tanh_fast(accA[jn][2]), (f16)tanh_fast(accA[jn][3]) }; \
        *(f16x4*)((H1W) + wroff[jn]) = t1v; \
    } \
    f32x4 accB[2]; \
    accB[0] = (f32x4){bi[0].x, bi[0].y, bi[0].z, bi[0].w}; \
    accB[1] = (f32x4){bi[1].x, bi[1].y, bi[1].z, bi[1].w}; \
    _Pragma("unroll") for (int kk = 0; kk < 8; kk++) { \
        f16x8 hb2 = *(const f16x8*)((H2R) + kk * 512 + lane * 8); \
        accB[0] = MF(wx [0][kk], hb1[kk], accB[0]); \
        accB[1] = MF(wx [1][kk], hb1[kk], accB[1]); \
        accB[0] = MF(wh1[0][kk], hb2, accB[0]); \
        accB[1] = MF(wh1[1][kk], hb2, accB[1]); \
    } \
    _Pragma("unroll") for (int jn = 0; jn < 2; jn++) { \
        f16x4 t2v = { (f16)tanh_fast(accB[jn][0]), (f16)tanh_fast(accB[jn][1]), \
                      (f16)tanh_fast(accB[jn][2]), (f16)tanh_fast(accB[jn][3]) }; \
        *(f16x4*)((H2W) + wroff[jn]) = t2v; \
    } \
    wg_barrier(); \
}

    // --- peeled i = 0: h1[0] only (h2[-1] stays zero) ---
    {
        UNPACK_ACCA
        PREFETCH(0)
        #pragma unroll
        for (int kk = 0; kk < 8; kk++) {
            f16x8 hb = *(const f16x8*)(h1f1 + kk * 512 + lane * 8);  // zeros
            accA[0] = MF(wh0[0][kk], hb, accA[0]);
            accA[1] = MF(wh0[1][kk], hb, accA[1]);
        }
        #pragma unroll
        for (int jn = 0; jn < 2; jn++) {
            f16x4 t1v = { (f16)tanh_fast(accA[jn][0]), (f16)tanh_fast(accA[jn][1]),
                          (f16)tanh_fast(accA[jn][2]), (f16)tanh_fast(accA[jn][3]) };
            *(f16x4*)(h1f0 + wroff[jn]) = t1v;
        }
        wg_barrier();
    }

    // --- steady state: i = 1..1022 ---
    #pragma unroll 1
    for (int tp = 0; tp < 511; ++tp) {
        FSTEP(h1f0, h1f1, h2f1, h2f0, (2 * tp + 1))
        FSTEP(h1f1, h1f0, h2f0, h2f1, (2 * tp + 2))
    }
    // --- i = 1023 ---
    FSTEP_LAST(h1f0, h1f1, h2f1, h2f0)
#undef FSTEP
#undef FSTEP_LAST
#undef PREFETCH
#undef UNPACK_ACCA

    // --- peeled i = 1024: h2[1023] = tanh(b1 + Wxh1.h1[1023] + Whh1.h2[1022])
    {
        f32x4 accB[2];
        accB[0] = (f32x4){bi[0].x, bi[0].y, bi[0].z, bi[0].w};
        accB[1] = (f32x4){bi[1].x, bi[1].y, bi[1].z, bi[1].w};
        #pragma unroll
        for (int kk = 0; kk < 8; kk++) {
            f16x8 hb1 = *(const f16x8*)(h1f1 + kk * 512 + lane * 8);  // h1[1023]
            f16x8 hb2 = *(const f16x8*)(h2f0 + kk * 512 + lane * 8);  // h2[1022]
            accB[0] = MF(wx [0][kk], hb1, accB[0]);
            accB[1] = MF(wx [1][kk], hb1, accB[1]);
            accB[0] = MF(wh1[0][kk], hb2, accB[0]);
            accB[1] = MF(wh1[1][kk], hb2, accB[1]);
        }
        #pragma unroll
        for (int jn = 0; jn < 2; jn++) {
            f16x4 t2v = { (f16)tanh_fast(accB[jn][0]), (f16)tanh_fast(accB[jn][1]),
                          (f16)tanh_fast(accB[jn][2]), (f16)tanh_fast(accB[jn][3]) };
            *(f16x4*)(h2f1 + wroff[jn]) = t2v;
        }
        wg_barrier();
    }

    // head: final h2[1023] in h2f1; frag-major.
    if (tid < 256) {
        const int bl = tid >> 4, o = (tid >> 3) & 1, kc = tid & 7;
        float s = 0.f;
        #pragma unroll
        for (int kq = 0; kq < 32; kq++) {
            int k = kc * 32 + kq;
            f16 hv = h2f1[(k >> 5) * 512 + ((k >> 3) & 3) * 128 + bl * 8 + (k & 7)];
            s += (float)hv * fcw[o * Hn + k];
        }
        s += __shfl_down(s, 4);
        s += __shfl_down(s, 2);
        s += __shfl_down(s, 1);
        if (kc == 0)
            out[(bg + bl) * 2 + o] = s + fcb[o];
    }

    // flag self-clean: LAST of the 8 recurrent WGs (all consumers provably
    // done) resets g_pflag + g_done for the next launch / graph replay.
    __syncthreads();
    if (tid == 0) {
        int old = atomicAdd(&g_done, 1);
        sflag = (old == 7) ? 1 : 0;
    }
    __syncthreads();
    if (sflag) {
        for (int i = tid; i < 1032; i += 512) ASTORE(&g_pflag[i], 0);
        if (tid == 0) ASTORE(&g_done, 0);
    }
}

extern "C" void kernel_launch(void* const* d_in, const int* in_sizes, int n_in,
                              void* d_out, int out_size, void* d_ws, size_t ws_size,
                              hipStream_t stream) {
    const float* x    = (const float*)d_in[0];
    const float* Wxh0 = (const float*)d_in[1];
    const float* Whh0 = (const float*)d_in[2];
    const float* b0   = (const float*)d_in[3];
    const float* Wxh1 = (const float*)d_in[4];
    const float* Whh1 = (const float*)d_in[5];
    const float* b1   = (const float*)d_in[6];
    const float* fcw  = (const float*)d_in[7];
    const float* fcb  = (const float*)d_in[8];
    float* out = (float*)d_out;

    float* preT = (float*)d_ws;  // pre[t][b][j] fp32 = 128 MiB

    k_all<<<dim3(256), dim3(512), 0, stream>>>(x, Wxh0, b0, Whh0, Wxh1, Whh1,
                                               b1, fcw, fcb, preT, out);
}